// Round 4
// baseline (444.691 us; speedup 1.0000x reference)
//
#include <hip/hip_runtime.h>

#define NNODES 50000
#define NEDGES 800000
#define IN_C   512
#define HID_C  128
#define OUT_C  64

typedef float  f32x4  __attribute__((ext_vector_type(4)));
typedef __bf16 bf16x8 __attribute__((ext_vector_type(8)));
typedef short  short8 __attribute__((ext_vector_type(8)));

// ---------------- graph prep ----------------

__global__ void init_kernel(float* __restrict__ deg, int* __restrict__ counts, int n) {
  int i = blockIdx.x * blockDim.x + threadIdx.x;
  if (i < n) { deg[i] = 1.0f; counts[i] = 1; }   // self-loop: weight 1, one CSR slot
}

__global__ void deg_count_kernel(const int* __restrict__ ei, const float* __restrict__ ew,
                                 float* __restrict__ deg, int* __restrict__ counts, int nE) {
  int e = blockIdx.x * blockDim.x + threadIdx.x;
  if (e < nE) {
    int c = ei[nE + e];               // edge_index[1][e] (destination)
    atomicAdd(&deg[c], ew[e]);
    atomicAdd(&counts[c], 1);
  }
}

__global__ void dinv_kernel(float* __restrict__ deg, int n) {
  int i = blockIdx.x * blockDim.x + threadIdx.x;
  if (i < n) { float d = deg[i]; deg[i] = d > 0.f ? rsqrtf(d) : 0.f; }
}

// single-block chunked exclusive scan over counts -> offs[0..n]
__global__ void __launch_bounds__(1024) scan_kernel(const int* __restrict__ counts,
                                                    int* __restrict__ offs, int n) {
  const int T = 1024;
  int t = threadIdx.x;
  int chunk = (n + T - 1) / T;
  int s0 = t * chunk; if (s0 > n) s0 = n;
  int s1 = s0 + chunk; if (s1 > n) s1 = n;
  int sum = 0;
  for (int i = s0; i < s1; ++i) sum += counts[i];
  __shared__ int lds[T];
  lds[t] = sum;
  __syncthreads();
  for (int off = 1; off < T; off <<= 1) {
    int v = (t >= off) ? lds[t - off] : 0;
    __syncthreads();
    lds[t] += v;
    __syncthreads();
  }
  int prefix = (t > 0) ? lds[t - 1] : 0;   // exclusive prefix of this chunk
  for (int i = s0; i < s1; ++i) { offs[i] = prefix; prefix += counts[i]; }
  if (t == T - 1) offs[n] = lds[T - 1];
}

__global__ void copy_int_kernel(const int* __restrict__ src, int* __restrict__ dst, int n) {
  int i = blockIdx.x * blockDim.x + threadIdx.x;
  if (i < n) dst[i] = src[i];
}

// fill CSR (sorted by destination): rows[] = source node, norms[] = dinv[r]*w*dinv[c]
__global__ void fill_kernel(const int* __restrict__ ei, const float* __restrict__ ew,
                            const float* __restrict__ dinv, int* __restrict__ cursor,
                            int* __restrict__ rows, float* __restrict__ norms,
                            int nE, int nN) {
  int i = blockIdx.x * blockDim.x + threadIdx.x;
  if (i < nN) {                       // self-loop of node i
    float di = dinv[i];
    int pos = atomicAdd(&cursor[i], 1);
    rows[pos] = i;
    norms[pos] = di * di;
  } else if (i < nN + nE) {
    int e = i - nN;
    int r = ei[e], c = ei[nE + e];
    float w = dinv[r] * ew[e] * dinv[c];
    int pos = atomicAdd(&cursor[c], 1);
    rows[pos] = r;
    norms[pos] = w;
  }
}

// ---------------- W split+transpose: W[K][N] f32 -> Wt hi/lo [N][K] bf16 ----------------

__global__ void wsplit_kernel(const float* __restrict__ W, unsigned short* __restrict__ Th,
                              unsigned short* __restrict__ Tl, int K, int N) {
  int id = blockIdx.x * blockDim.x + threadIdx.x;
  if (id >= K * N) return;
  int k = id % K, n = id / K;           // consecutive id -> consecutive k -> coalesced writes
  float f = W[(size_t)k * N + n];
  __bf16 hb = (__bf16)f;
  float hf = (float)hb;
  __bf16 lb = (__bf16)(f - hf);
  Th[id] = __builtin_bit_cast(unsigned short, hb);
  Tl[id] = __builtin_bit_cast(unsigned short, lb);
}

// ---------------- split-bf16 MFMA GEMM, register-pipelined ----------------
// Y[M,N] = X[M,K] @ W[K,N];  Y ~= Xh@Wh + Xl@Wh + Xh@Wl  (Xl@Wl dropped, ~2^-18)
// LDS-free; W^T hi/lo bf16 L2-resident. Block = 256 threads = 4 waves.
// Wave tile = (MF*16) x 64.  NWC = N/64 col-waves, NWR = 4/NWC row-waves.
// Explicit 1-deep register double-buffer: load(ks+1) issued before compute(ks).
template <int K, int N, int MF>
__global__ void __launch_bounds__(256, 3) gemm_mfma_kernel(
    const float* __restrict__ X, const unsigned short* __restrict__ Bth,
    const unsigned short* __restrict__ Btl, float* __restrict__ Y, int M) {
  constexpr int NWC = N / 64;
  constexpr int NWR = 4 / NWC;
  constexpr int BROWS = NWR * MF * 16;
  constexpr int NI = K / 32;            // K-steps (even)
  int tid = threadIdx.x;
  int lane = tid & 63, wid = tid >> 6;
  int wr = wid / NWC, wc = wid % NWC;
  int row0 = blockIdx.x * BROWS + wr * (MF * 16);
  int rlo = lane & 15;
  int khi = lane >> 4;

  int arow[MF];
#pragma unroll
  for (int m = 0; m < MF; ++m) {
    int r = row0 + m * 16 + rlo;
    arow[m] = r < M ? r : M - 1;        // clamp; stores guarded below
  }
  int bcol = wc * 64 + rlo;

  f32x4 acc[MF][4] = {};

  float4 arA[MF][2], arB[MF][2];
  short8 bhA[4], blA[4], bhB[4], blB[4];

  auto load = [&](int ks, float4 (&ar)[MF][2], short8 (&bh)[4], short8 (&bl)[4]) {
    int kb = ks * 32 + khi * 8;
#pragma unroll
    for (int m = 0; m < MF; ++m) {
      const float* src = X + (size_t)arow[m] * K + kb;
      ar[m][0] = *reinterpret_cast<const float4*>(src);
      ar[m][1] = *reinterpret_cast<const float4*>(src + 4);
    }
#pragma unroll
    for (int n = 0; n < 4; ++n) {
      size_t off = (size_t)(bcol + n * 16) * K + kb;
      bh[n] = *reinterpret_cast<const short8*>(Bth + off);
      bl[n] = *reinterpret_cast<const short8*>(Btl + off);
    }
  };

  auto compute = [&](float4 (&ar)[MF][2], short8 (&bh)[4], short8 (&bl)[4]) {
    bf16x8 ah[MF], al[MF];
#pragma unroll
    for (int m = 0; m < MF; ++m) {
      float f[8] = {ar[m][0].x, ar[m][0].y, ar[m][0].z, ar[m][0].w,
                    ar[m][1].x, ar[m][1].y, ar[m][1].z, ar[m][1].w};
#pragma unroll
      for (int i = 0; i < 8; ++i) {
        __bf16 hv = (__bf16)f[i];
        ah[m][i] = hv;
        al[m][i] = (__bf16)(f[i] - (float)hv);
      }
    }
    // term order: ah*bh (ready first), al*bh, ah*bl last (covers bl load latency)
#pragma unroll
    for (int m = 0; m < MF; ++m)
#pragma unroll
      for (int n = 0; n < 4; ++n)
        acc[m][n] = __builtin_amdgcn_mfma_f32_16x16x32_bf16(
            ah[m], __builtin_bit_cast(bf16x8, bh[n]), acc[m][n], 0, 0, 0);
#pragma unroll
    for (int m = 0; m < MF; ++m)
#pragma unroll
      for (int n = 0; n < 4; ++n)
        acc[m][n] = __builtin_amdgcn_mfma_f32_16x16x32_bf16(
            al[m], __builtin_bit_cast(bf16x8, bh[n]), acc[m][n], 0, 0, 0);
#pragma unroll
    for (int m = 0; m < MF; ++m)
#pragma unroll
      for (int n = 0; n < 4; ++n)
        acc[m][n] = __builtin_amdgcn_mfma_f32_16x16x32_bf16(
            ah[m], __builtin_bit_cast(bf16x8, bl[n]), acc[m][n], 0, 0, 0);
  };

  load(0, arA, bhA, blA);
#pragma unroll 1
  for (int it = 0; it < NI / 2; ++it) {
    load(2 * it + 1, arB, bhB, blB);    // prefetch odd step
    compute(arA, bhA, blA);
    if (2 * it + 2 < NI)
      load(2 * it + 2, arA, bhA, blA);  // prefetch next even step
    compute(arB, bhB, blB);
  }

  // C/D layout: col = lane&15, row = (lane>>4)*4 + reg  [m89-verified]
#pragma unroll
  for (int m = 0; m < MF; ++m)
#pragma unroll
    for (int j = 0; j < 4; ++j) {
      int row = row0 + m * 16 + khi * 4 + j;
      if (row < M) {
#pragma unroll
        for (int n = 0; n < 4; ++n)
          Y[(size_t)row * N + wc * 64 + n * 16 + rlo] = acc[m][n][j];
      }
    }
}

// ---------------- CSR aggregation: out[n] = bias + sum_e norm[e]*feat[rows[e]] ----------------
// one wave per node, 4 nodes per 256-thread block; lane covers F/64 features
template <int F, bool RELU>
__global__ void __launch_bounds__(256) agg_kernel(const float* __restrict__ feat,
                                                  const int* __restrict__ offs,
                                                  const int* __restrict__ rows,
                                                  const float* __restrict__ norms,
                                                  const float* __restrict__ bias,
                                                  float* __restrict__ out, int n) {
  constexpr int VEC = F / 64;   // 2 (F=128) or 1 (F=64)
  int wid = threadIdx.x >> 6;
  int lane = threadIdx.x & 63;
  int node = blockIdx.x * 4 + wid;
  if (node >= n) return;
  int e0 = offs[node], e1 = offs[node + 1];

  if constexpr (VEC == 2) {
    float2 acc = *reinterpret_cast<const float2*>(&bias[lane * 2]);
    int e = e0;
    for (; e + 1 < e1; e += 2) {
      int r0 = rows[e], r1 = rows[e + 1];
      float w0 = norms[e], w1 = norms[e + 1];
      float2 f0 = *reinterpret_cast<const float2*>(&feat[(size_t)r0 * F + lane * 2]);
      float2 f1 = *reinterpret_cast<const float2*>(&feat[(size_t)r1 * F + lane * 2]);
      acc.x = fmaf(w0, f0.x, acc.x); acc.y = fmaf(w0, f0.y, acc.y);
      acc.x = fmaf(w1, f1.x, acc.x); acc.y = fmaf(w1, f1.y, acc.y);
    }
    if (e < e1) {
      int r0 = rows[e]; float w0 = norms[e];
      float2 f0 = *reinterpret_cast<const float2*>(&feat[(size_t)r0 * F + lane * 2]);
      acc.x = fmaf(w0, f0.x, acc.x); acc.y = fmaf(w0, f0.y, acc.y);
    }
    if (RELU) { acc.x = fmaxf(acc.x, 0.f); acc.y = fmaxf(acc.y, 0.f); }
    *reinterpret_cast<float2*>(&out[(size_t)node * F + lane * 2]) = acc;
  } else {
    float acc = bias[lane];
    int e = e0;
    for (; e + 1 < e1; e += 2) {
      int r0 = rows[e], r1 = rows[e + 1];
      float w0 = norms[e], w1 = norms[e + 1];
      float f0 = feat[(size_t)r0 * F + lane];
      float f1 = feat[(size_t)r1 * F + lane];
      acc = fmaf(w0, f0, acc);
      acc = fmaf(w1, f1, acc);
    }
    if (e < e1) {
      acc = fmaf(norms[e], feat[(size_t)rows[e] * F + lane], acc);
    }
    if (RELU) acc = fmaxf(acc, 0.f);
    out[(size_t)node * F + lane] = acc;
  }
}

// ---------------- launch ----------------

extern "C" void kernel_launch(void* const* d_in, const int* in_sizes, int n_in,
                              void* d_out, int out_size, void* d_ws, size_t ws_size,
                              hipStream_t stream) {
  const float* x  = (const float*)d_in[0];
  const int*   ei = (const int*)d_in[1];     // [2, E] int
  const float* ew = (const float*)d_in[2];
  const float* W1 = (const float*)d_in[3];
  const float* b1 = (const float*)d_in[4];
  const float* W2 = (const float*)d_in[5];
  const float* b2 = (const float*)d_in[6];
  float* out = (float*)d_out;

  const int N = NNODES, E = NEDGES, EP = NNODES + NEDGES;

  char* p = (char*)d_ws;
  auto alloc = [&](size_t bytes) { char* r = p; p += (bytes + 255) & ~(size_t)255; return r; };
  float* deg    = (float*)alloc((size_t)N * 4);        // becomes dinv in-place
  int*   counts = (int*)  alloc((size_t)N * 4);
  int*   offs   = (int*)  alloc((size_t)(N + 1) * 4);
  int*   cursor = (int*)  alloc((size_t)N * 4);
  int*   rows   = (int*)  alloc((size_t)EP * 4);
  float* norms  = (float*)alloc((size_t)EP * 4);
  float* xw     = (float*)alloc((size_t)N * HID_C * 4); // layer1 pre-agg; reused as h2
  float* h      = (float*)alloc((size_t)N * HID_C * 4); // layer1 output
  unsigned short* W1th = (unsigned short*)alloc((size_t)IN_C * HID_C * 2);
  unsigned short* W1tl = (unsigned short*)alloc((size_t)IN_C * HID_C * 2);
  unsigned short* W2th = (unsigned short*)alloc((size_t)HID_C * OUT_C * 2);
  unsigned short* W2tl = (unsigned short*)alloc((size_t)HID_C * OUT_C * 2);

  init_kernel<<<(N + 255) / 256, 256, 0, stream>>>(deg, counts, N);
  deg_count_kernel<<<(E + 255) / 256, 256, 0, stream>>>(ei, ew, deg, counts, E);
  dinv_kernel<<<(N + 255) / 256, 256, 0, stream>>>(deg, N);
  scan_kernel<<<1, 1024, 0, stream>>>(counts, offs, N);
  copy_int_kernel<<<(N + 255) / 256, 256, 0, stream>>>(offs, cursor, N);
  fill_kernel<<<(EP + 255) / 256, 256, 0, stream>>>(ei, ew, deg, cursor, rows, norms, E, N);
  wsplit_kernel<<<(IN_C * HID_C + 255) / 256, 256, 0, stream>>>(W1, W1th, W1tl, IN_C, HID_C);
  wsplit_kernel<<<(HID_C * OUT_C + 255) / 256, 256, 0, stream>>>(W2, W2th, W2tl, HID_C, OUT_C);

  const int gemm_grid = (N + 63) / 64;   // BROWS=64 for both instantiations
  // layer 1: xw = x @ W1 ; h = relu(agg(xw) + b1)
  gemm_mfma_kernel<IN_C, HID_C, 2><<<gemm_grid, 256, 0, stream>>>(x, W1th, W1tl, xw, N);
  agg_kernel<HID_C, true><<<(N + 3) / 4, 256, 0, stream>>>(xw, offs, rows, norms, b1, h, N);

  // layer 2: h2 = h @ W2 ; out = agg(h2) + b2
  gemm_mfma_kernel<HID_C, OUT_C, 1><<<gemm_grid, 256, 0, stream>>>(h, W2th, W2tl, xw, N);
  agg_kernel<OUT_C, false><<<(N + 3) / 4, 256, 0, stream>>>(xw, offs, rows, norms, b2, out, N);
}

// Round 5
// 387.631 us; speedup vs baseline: 1.1472x; 1.1472x over previous
//
#include <hip/hip_runtime.h>

#define NNODES 50000
#define NEDGES 800000
#define IN_C   512
#define HID_C  128
#define OUT_C  64

typedef float  f32x4  __attribute__((ext_vector_type(4)));
typedef __bf16 bf16x8 __attribute__((ext_vector_type(8)));
typedef short  short8 __attribute__((ext_vector_type(8)));

// ---------------- graph prep ----------------

__global__ void init_kernel(float* __restrict__ deg, int* __restrict__ counts, int n) {
  int i = blockIdx.x * blockDim.x + threadIdx.x;
  if (i < n) { deg[i] = 1.0f; counts[i] = 1; }   // self-loop: weight 1, one CSR slot
}

__global__ void deg_count_kernel(const int* __restrict__ ei, const float* __restrict__ ew,
                                 float* __restrict__ deg, int* __restrict__ counts, int nE) {
  int e = blockIdx.x * blockDim.x + threadIdx.x;
  if (e < nE) {
    int c = ei[nE + e];               // edge_index[1][e] (destination)
    atomicAdd(&deg[c], ew[e]);
    atomicAdd(&counts[c], 1);
  }
}

__global__ void dinv_kernel(float* __restrict__ deg, int n) {
  int i = blockIdx.x * blockDim.x + threadIdx.x;
  if (i < n) { float d = deg[i]; deg[i] = d > 0.f ? rsqrtf(d) : 0.f; }
}

// single-block chunked exclusive scan over counts -> offs[0..n]
__global__ void __launch_bounds__(1024) scan_kernel(const int* __restrict__ counts,
                                                    int* __restrict__ offs, int n) {
  const int T = 1024;
  int t = threadIdx.x;
  int chunk = (n + T - 1) / T;
  int s0 = t * chunk; if (s0 > n) s0 = n;
  int s1 = s0 + chunk; if (s1 > n) s1 = n;
  int sum = 0;
  for (int i = s0; i < s1; ++i) sum += counts[i];
  __shared__ int lds[T];
  lds[t] = sum;
  __syncthreads();
  for (int off = 1; off < T; off <<= 1) {
    int v = (t >= off) ? lds[t - off] : 0;
    __syncthreads();
    lds[t] += v;
    __syncthreads();
  }
  int prefix = (t > 0) ? lds[t - 1] : 0;   // exclusive prefix of this chunk
  for (int i = s0; i < s1; ++i) { offs[i] = prefix; prefix += counts[i]; }
  if (t == T - 1) offs[n] = lds[T - 1];
}

__global__ void copy_int_kernel(const int* __restrict__ src, int* __restrict__ dst, int n) {
  int i = blockIdx.x * blockDim.x + threadIdx.x;
  if (i < n) dst[i] = src[i];
}

// fill CSR (sorted by destination): rows[] = source node, norms[] = dinv[r]*w*dinv[c]
__global__ void fill_kernel(const int* __restrict__ ei, const float* __restrict__ ew,
                            const float* __restrict__ dinv, int* __restrict__ cursor,
                            int* __restrict__ rows, float* __restrict__ norms,
                            int nE, int nN) {
  int i = blockIdx.x * blockDim.x + threadIdx.x;
  if (i < nN) {                       // self-loop of node i
    float di = dinv[i];
    int pos = atomicAdd(&cursor[i], 1);
    rows[pos] = i;
    norms[pos] = di * di;
  } else if (i < nN + nE) {
    int e = i - nN;
    int r = ei[e], c = ei[nE + e];
    float w = dinv[r] * ew[e] * dinv[c];
    int pos = atomicAdd(&cursor[c], 1);
    rows[pos] = r;
    norms[pos] = w;
  }
}

// ---------------- W split+transpose: W[K][N] f32 -> Wt hi/lo [N][K] bf16 ----------------

__global__ void wsplit_kernel(const float* __restrict__ W, unsigned short* __restrict__ Th,
                              unsigned short* __restrict__ Tl, int K, int N) {
  int id = blockIdx.x * blockDim.x + threadIdx.x;
  if (id >= K * N) return;
  int k = id % K, n = id / K;           // consecutive id -> consecutive k -> coalesced writes
  float f = W[(size_t)k * N + n];
  __bf16 hb = (__bf16)f;
  float hf = (float)hb;
  __bf16 lb = (__bf16)(f - hf);
  Th[id] = __builtin_bit_cast(unsigned short, hb);
  Tl[id] = __builtin_bit_cast(unsigned short, lb);
}

// ---------------- split-bf16 MFMA GEMM, 2-phase LDS pipeline ----------------
// Y[M,N] = X[M,K] @ W[K,N];  Y ~= Xh@Wh + Xl@Wh + Xh@Wl  (Xl@Wl dropped, ~2^-18)
// A-tile (f32) staged via global_load_lds (16B), double-buffered LDS.
// LDS dest is linear (wave-uniform base + lane*16, m104); the bank-conflict fix is an
// XOR granule swizzle applied on the GLOBAL SOURCE address and undone on ds_read (rule #21).
// B = W^T hi/lo bf16, register-loaded from L2, issued BEFORE the stage so the compiler's
// counted vmcnt for B does not drain the in-flight stage (vmcnt retires in order).
template <int K, int N, int MF>
__global__ void __launch_bounds__(256, 3) gemm_mfma_kernel(
    const float* __restrict__ X, const unsigned short* __restrict__ Bth,
    const unsigned short* __restrict__ Btl, float* __restrict__ Y, int M) {
  constexpr int NWC = N / 64;           // col-wave groups
  constexpr int NWR = 4 / NWC;          // row waves
  constexpr int BM = NWR * MF * 16;     // 64 (gemm1) / 128 (gemm2)
  constexpr int BK = 64;                // K-chunk (floats)
  constexpr int NI = K / BK;            // 8 / 2
  constexpr int IPW = BM / 16;          // global_load_lds issues per wave (4 / 8)

  __shared__ float As[2][BM * BK];      // 32KB / 64KB

  int tid = threadIdx.x;
  int lane = tid & 63, wid = tid >> 6;
  int wr = wid / NWC, wc = wid % NWC;
  int row0blk = blockIdx.x * BM;
  int row0 = row0blk + wr * (MF * 16);
  int rlo = lane & 15;
  int khi = lane >> 4;
  int bcol = wc * 64 + rlo;

  f32x4 acc[MF][4] = {};

  // stage K-chunk ks into buffer buf (all 4 waves; 1KB = 4 rows per issue)
  auto stage = [&](int ks, int buf) {
    int kb = ks * BK;
#pragma unroll
    for (int i = 0; i < IPW; ++i) {
      int slot = wid * IPW + i;               // 1KB slot
      int rt = slot * 4 + (lane >> 4);        // row in tile (0..BM-1)
      int gr = row0blk + rt; gr = gr < M ? gr : M - 1;
      int gd = (lane & 15) ^ (rt & 15);       // swizzled source granule (16B units)
      const float* src = X + (size_t)gr * K + kb + gd * 4;
      float* dst = &As[buf][slot * 256];      // wave-uniform; HW adds lane*16B
      __builtin_amdgcn_global_load_lds(
          (const __attribute__((address_space(1))) unsigned int*)src,
          (__attribute__((address_space(3))) unsigned int*)dst, 16, 0, 0);
    }
  };

  stage(0, 0);
  __syncthreads();

#pragma unroll 1
  for (int t = 0; t < NI; ++t) {
    int buf = t & 1;
    int kb = t * BK;
    // B register loads FIRST (so stage loads below stay outstanding past B's waits)
    short8 bh[2][4], bl[2][4];
#pragma unroll
    for (int ks2 = 0; ks2 < 2; ++ks2)
#pragma unroll
      for (int n = 0; n < 4; ++n) {
        size_t off = (size_t)(bcol + n * 16) * K + kb + ks2 * 32 + khi * 8;
        bh[ks2][n] = *reinterpret_cast<const short8*>(Bth + off);
        bl[ks2][n] = *reinterpret_cast<const short8*>(Btl + off);
      }
    if (t + 1 < NI) stage(t + 1, buf ^ 1);

    // A fragments from LDS (un-swizzle), convert f32 -> bf16 hi/lo, MFMA
    const float* bp = &As[buf][0];
#pragma unroll
    for (int ks2 = 0; ks2 < 2; ++ks2) {
      bf16x8 ah[MF], al[MF];
#pragma unroll
      for (int m = 0; m < MF; ++m) {
        int rt = wr * 32 + m * 16 + rlo;
        int g0 = ks2 * 8 + khi * 2;
        f32x4 v0 = *reinterpret_cast<const f32x4*>(&bp[rt * 64 + ((g0    ) ^ (rt & 15)) * 4]);
        f32x4 v1 = *reinterpret_cast<const f32x4*>(&bp[rt * 64 + ((g0 + 1) ^ (rt & 15)) * 4]);
        float f[8] = {v0.x, v0.y, v0.z, v0.w, v1.x, v1.y, v1.z, v1.w};
#pragma unroll
        for (int i = 0; i < 8; ++i) {
          __bf16 hv = (__bf16)f[i];
          ah[m][i] = hv;
          al[m][i] = (__bf16)(f[i] - (float)hv);
        }
      }
#pragma unroll
      for (int m = 0; m < MF; ++m)
#pragma unroll
        for (int n = 0; n < 4; ++n) {
          acc[m][n] = __builtin_amdgcn_mfma_f32_16x16x32_bf16(
              ah[m], __builtin_bit_cast(bf16x8, bh[ks2][n]), acc[m][n], 0, 0, 0);
          acc[m][n] = __builtin_amdgcn_mfma_f32_16x16x32_bf16(
              al[m], __builtin_bit_cast(bf16x8, bh[ks2][n]), acc[m][n], 0, 0, 0);
          acc[m][n] = __builtin_amdgcn_mfma_f32_16x16x32_bf16(
              ah[m], __builtin_bit_cast(bf16x8, bl[ks2][n]), acc[m][n], 0, 0, 0);
        }
    }
    __syncthreads();   // drains stage(t+1) (vmcnt 0) + frees buf for overwrite
  }

  // C/D layout: col = lane&15, row = (lane>>4)*4 + reg  [m89-verified]
#pragma unroll
  for (int m = 0; m < MF; ++m)
#pragma unroll
    for (int j = 0; j < 4; ++j) {
      int row = row0 + m * 16 + khi * 4 + j;
      if (row < M) {
#pragma unroll
        for (int n = 0; n < 4; ++n)
          Y[(size_t)row * N + wc * 64 + n * 16 + rlo] = acc[m][n][j];
      }
    }
}

// ---------------- CSR aggregation: out[n] = bias + sum_e norm[e]*feat[rows[e]] ----------------
// F/4 lanes per node (float4 loads), 4-deep edge unroll for memory-level parallelism
template <int F, bool RELU>
__global__ void __launch_bounds__(256) agg_kernel(const float* __restrict__ feat,
                                                  const int* __restrict__ offs,
                                                  const int* __restrict__ rows,
                                                  const float* __restrict__ norms,
                                                  const float* __restrict__ bias,
                                                  float* __restrict__ out, int n) {
  constexpr int LPN = F / 4;        // lanes per node (32 for F=128, 16 for F=64)
  constexpr int NPW = 64 / LPN;     // nodes per wave (2 / 4)
  constexpr int NPB = 4 * NPW;      // nodes per 256-thread block
  int wid = threadIdx.x >> 6;
  int lane = threadIdx.x & 63;
  int node = blockIdx.x * NPB + wid * NPW + lane / LPN;
  int lf = (lane % LPN) * 4;        // feature offset
  if (node >= n) return;
  int e0 = offs[node], e1 = offs[node + 1];

  float4 acc = *reinterpret_cast<const float4*>(&bias[lf]);
  int e = e0;
  for (; e + 4 <= e1; e += 4) {
    int r0 = rows[e], r1 = rows[e + 1], r2 = rows[e + 2], r3 = rows[e + 3];
    float w0 = norms[e], w1 = norms[e + 1], w2 = norms[e + 2], w3 = norms[e + 3];
    float4 f0 = *reinterpret_cast<const float4*>(&feat[(size_t)r0 * F + lf]);
    float4 f1 = *reinterpret_cast<const float4*>(&feat[(size_t)r1 * F + lf]);
    float4 f2 = *reinterpret_cast<const float4*>(&feat[(size_t)r2 * F + lf]);
    float4 f3 = *reinterpret_cast<const float4*>(&feat[(size_t)r3 * F + lf]);
    acc.x = fmaf(w0, f0.x, acc.x); acc.y = fmaf(w0, f0.y, acc.y);
    acc.z = fmaf(w0, f0.z, acc.z); acc.w = fmaf(w0, f0.w, acc.w);
    acc.x = fmaf(w1, f1.x, acc.x); acc.y = fmaf(w1, f1.y, acc.y);
    acc.z = fmaf(w1, f1.z, acc.z); acc.w = fmaf(w1, f1.w, acc.w);
    acc.x = fmaf(w2, f2.x, acc.x); acc.y = fmaf(w2, f2.y, acc.y);
    acc.z = fmaf(w2, f2.z, acc.z); acc.w = fmaf(w2, f2.w, acc.w);
    acc.x = fmaf(w3, f3.x, acc.x); acc.y = fmaf(w3, f3.y, acc.y);
    acc.z = fmaf(w3, f3.z, acc.z); acc.w = fmaf(w3, f3.w, acc.w);
  }
  for (; e < e1; ++e) {
    int r = rows[e];
    float w = norms[e];
    float4 f = *reinterpret_cast<const float4*>(&feat[(size_t)r * F + lf]);
    acc.x = fmaf(w, f.x, acc.x); acc.y = fmaf(w, f.y, acc.y);
    acc.z = fmaf(w, f.z, acc.z); acc.w = fmaf(w, f.w, acc.w);
  }
  if (RELU) {
    acc.x = fmaxf(acc.x, 0.f); acc.y = fmaxf(acc.y, 0.f);
    acc.z = fmaxf(acc.z, 0.f); acc.w = fmaxf(acc.w, 0.f);
  }
  *reinterpret_cast<float4*>(&out[(size_t)node * F + lf]) = acc;
}

// ---------------- launch ----------------

extern "C" void kernel_launch(void* const* d_in, const int* in_sizes, int n_in,
                              void* d_out, int out_size, void* d_ws, size_t ws_size,
                              hipStream_t stream) {
  const float* x  = (const float*)d_in[0];
  const int*   ei = (const int*)d_in[1];     // [2, E] int
  const float* ew = (const float*)d_in[2];
  const float* W1 = (const float*)d_in[3];
  const float* b1 = (const float*)d_in[4];
  const float* W2 = (const float*)d_in[5];
  const float* b2 = (const float*)d_in[6];
  float* out = (float*)d_out;

  const int N = NNODES, E = NEDGES, EP = NNODES + NEDGES;

  char* p = (char*)d_ws;
  auto alloc = [&](size_t bytes) { char* r = p; p += (bytes + 255) & ~(size_t)255; return r; };
  float* deg    = (float*)alloc((size_t)N * 4);        // becomes dinv in-place
  int*   counts = (int*)  alloc((size_t)N * 4);
  int*   offs   = (int*)  alloc((size_t)(N + 1) * 4);
  int*   cursor = (int*)  alloc((size_t)N * 4);
  int*   rows   = (int*)  alloc((size_t)EP * 4);
  float* norms  = (float*)alloc((size_t)EP * 4);
  float* xw     = (float*)alloc((size_t)N * HID_C * 4); // layer1 pre-agg; reused as h2
  float* h      = (float*)alloc((size_t)N * HID_C * 4); // layer1 output
  unsigned short* W1th = (unsigned short*)alloc((size_t)IN_C * HID_C * 2);
  unsigned short* W1tl = (unsigned short*)alloc((size_t)IN_C * HID_C * 2);
  unsigned short* W2th = (unsigned short*)alloc((size_t)HID_C * OUT_C * 2);
  unsigned short* W2tl = (unsigned short*)alloc((size_t)HID_C * OUT_C * 2);

  init_kernel<<<(N + 255) / 256, 256, 0, stream>>>(deg, counts, N);
  deg_count_kernel<<<(E + 255) / 256, 256, 0, stream>>>(ei, ew, deg, counts, E);
  dinv_kernel<<<(N + 255) / 256, 256, 0, stream>>>(deg, N);
  scan_kernel<<<1, 1024, 0, stream>>>(counts, offs, N);
  copy_int_kernel<<<(N + 255) / 256, 256, 0, stream>>>(offs, cursor, N);
  fill_kernel<<<(EP + 255) / 256, 256, 0, stream>>>(ei, ew, deg, cursor, rows, norms, E, N);
  wsplit_kernel<<<(IN_C * HID_C + 255) / 256, 256, 0, stream>>>(W1, W1th, W1tl, IN_C, HID_C);
  wsplit_kernel<<<(HID_C * OUT_C + 255) / 256, 256, 0, stream>>>(W2, W2th, W2tl, HID_C, OUT_C);

  // layer 1: xw = x @ W1 ; h = relu(agg(xw) + b1)
  gemm_mfma_kernel<IN_C, HID_C, 2><<<(N + 63) / 64, 256, 0, stream>>>(x, W1th, W1tl, xw, N);
  agg_kernel<HID_C, true><<<(N + 7) / 8, 256, 0, stream>>>(xw, offs, rows, norms, b1, h, N);

  // layer 2: h2 = h @ W2 ; out = agg(h2) + b2
  gemm_mfma_kernel<HID_C, OUT_C, 2><<<(N + 127) / 128, 256, 0, stream>>>(h, W2th, W2tl, xw, N);
  agg_kernel<OUT_C, false><<<(N + 15) / 16, 256, 0, stream>>>(xw, offs, rows, norms, b2, out, N);
}

// Round 6
// 357.668 us; speedup vs baseline: 1.2433x; 1.0838x over previous
//
#include <hip/hip_runtime.h>

#define NNODES 50000
#define NEDGES 800000
#define IN_C   512
#define HID_C  128
#define OUT_C  64

typedef float  f32x4  __attribute__((ext_vector_type(4)));
typedef __bf16 bf16x8 __attribute__((ext_vector_type(8)));
typedef short  short8 __attribute__((ext_vector_type(8)));

#define GLDS(src, dst) \
  __builtin_amdgcn_global_load_lds( \
      (const __attribute__((address_space(1))) unsigned int*)(src), \
      (__attribute__((address_space(3))) unsigned int*)(dst), 16, 0, 0)

// ---------------- graph prep ----------------

__global__ void init_kernel(float* __restrict__ deg, int* __restrict__ counts, int n) {
  int i = blockIdx.x * blockDim.x + threadIdx.x;
  if (i < n) { deg[i] = 1.0f; counts[i] = 1; }   // self-loop: weight 1, one CSR slot
}

__global__ void deg_count_kernel(const int* __restrict__ ei, const float* __restrict__ ew,
                                 float* __restrict__ deg, int* __restrict__ counts, int nE) {
  int e = blockIdx.x * blockDim.x + threadIdx.x;
  if (e < nE) {
    int c = ei[nE + e];               // edge_index[1][e] (destination)
    atomicAdd(&deg[c], ew[e]);
    atomicAdd(&counts[c], 1);
  }
}

__global__ void dinv_kernel(float* __restrict__ deg, int n) {
  int i = blockIdx.x * blockDim.x + threadIdx.x;
  if (i < n) { float d = deg[i]; deg[i] = d > 0.f ? rsqrtf(d) : 0.f; }
}

// single-block chunked exclusive scan over counts -> offs[0..n]
__global__ void __launch_bounds__(1024) scan_kernel(const int* __restrict__ counts,
                                                    int* __restrict__ offs, int n) {
  const int T = 1024;
  int t = threadIdx.x;
  int chunk = (n + T - 1) / T;
  int s0 = t * chunk; if (s0 > n) s0 = n;
  int s1 = s0 + chunk; if (s1 > n) s1 = n;
  int sum = 0;
  for (int i = s0; i < s1; ++i) sum += counts[i];
  __shared__ int lds[T];
  lds[t] = sum;
  __syncthreads();
  for (int off = 1; off < T; off <<= 1) {
    int v = (t >= off) ? lds[t - off] : 0;
    __syncthreads();
    lds[t] += v;
    __syncthreads();
  }
  int prefix = (t > 0) ? lds[t - 1] : 0;   // exclusive prefix of this chunk
  for (int i = s0; i < s1; ++i) { offs[i] = prefix; prefix += counts[i]; }
  if (t == T - 1) offs[n] = lds[T - 1];
}

__global__ void copy_int_kernel(const int* __restrict__ src, int* __restrict__ dst, int n) {
  int i = blockIdx.x * blockDim.x + threadIdx.x;
  if (i < n) dst[i] = src[i];
}

// fill CSR (sorted by destination): rows[] = source node, norms[] = dinv[r]*w*dinv[c]
__global__ void fill_kernel(const int* __restrict__ ei, const float* __restrict__ ew,
                            const float* __restrict__ dinv, int* __restrict__ cursor,
                            int* __restrict__ rows, float* __restrict__ norms,
                            int nE, int nN) {
  int i = blockIdx.x * blockDim.x + threadIdx.x;
  if (i < nN) {                       // self-loop of node i
    float di = dinv[i];
    int pos = atomicAdd(&cursor[i], 1);
    rows[pos] = i;
    norms[pos] = di * di;
  } else if (i < nN + nE) {
    int e = i - nN;
    int r = ei[e], c = ei[nE + e];
    float w = dinv[r] * ew[e] * dinv[c];
    int pos = atomicAdd(&cursor[c], 1);
    rows[pos] = r;
    norms[pos] = w;
  }
}

// ---------------- W split+transpose: W[K][N] f32 -> Wt hi/lo [N][K] bf16 ----------------

__global__ void wsplit_kernel(const float* __restrict__ W, unsigned short* __restrict__ Th,
                              unsigned short* __restrict__ Tl, int K, int N) {
  int id = blockIdx.x * blockDim.x + threadIdx.x;
  if (id >= K * N) return;
  int k = id % K, n = id / K;           // consecutive id -> consecutive k -> coalesced writes
  float f = W[(size_t)k * N + n];
  __bf16 hb = (__bf16)f;
  float hf = (float)hb;
  __bf16 lb = (__bf16)(f - hf);
  Th[id] = __builtin_bit_cast(unsigned short, hb);
  Tl[id] = __builtin_bit_cast(unsigned short, lb);
}

// ---------------- split-bf16 MFMA GEMM, 2-phase LDS pipeline, A+B both staged ----------------
// Y[M,N] = X[M,K] @ W[K,N];  Y ~= Xh@Wh + Xl@Wh + Xh@Wl  (Xl@Wl dropped, ~2^-18)
// Per K-chunk (BK=32): A f32 tile AND B=W^T hi/lo bf16 tiles staged via global_load_lds
// (16B), double-buffered, one __syncthreads per chunk (T3-minimum skeleton).
// Swizzles (rule #21, both sides): A granule ^= (row&7); B k-granule ^= ((col>>1)&3),
// applied on the global SOURCE address (LDS dest is linear) and undone on ds_read.
// Both read patterns land 2-way bank-aliased = free (m136).
template <int K, int N, int MF>
__global__ void __launch_bounds__(256, 3) gemm_mfma_kernel(
    const float* __restrict__ X, const unsigned short* __restrict__ Bth,
    const unsigned short* __restrict__ Btl, float* __restrict__ Y, int M) {
  constexpr int NWC = N / 64;           // col wave-groups (2 for N=128, 1 for N=64)
  constexpr int NWR = 4 / NWC;          // row waves
  constexpr int BM = NWR * MF * 16;     // 64
  constexpr int BK = 32;
  constexpr int NI = K / BK;
  constexpr int IPA = BM / 32;          // A gld_lds per wave (BM*128B / 1KB / 4 waves)
  constexpr int IPB = N / 64;           // B gld_lds per wave per half (BK*N*2B / 1KB / 4)

  __shared__ float          As [2][BM * BK];   // 2 x 8KB
  __shared__ unsigned short Bsh[2][BK * N];    // 2 x (8KB | 4KB)
  __shared__ unsigned short Bsl[2][BK * N];

  int tid = threadIdx.x;
  int lane = tid & 63, wid = tid >> 6;
  int wr = wid / NWC, wc = wid % NWC;
  int row0blk = blockIdx.x * BM;
  int row0 = row0blk + wr * (MF * 16);
  int rlo = lane & 15;
  int khi = lane >> 4;

  f32x4 acc[MF][4] = {};

  // stage K-chunk t into buffer buf (whole block cooperates)
  auto stage = [&](int t, int buf) {
    int kb = t * BK;
    // A: 1KB slot = 8 rows x 32 floats; src granule XOR row&7 (slot*8 keeps row&7 = lane>>3)
#pragma unroll
    for (int i = 0; i < IPA; ++i) {
      int slot = wid * IPA + i;
      int rt = slot * 8 + (lane >> 3);
      int gr = row0blk + rt; gr = gr < M ? gr : M - 1;
      int gs = (lane & 7) ^ ((lane >> 3) & 7);
      GLDS(X + (size_t)gr * K + kb + gs * 4, &As[buf][slot * 256]);
    }
    // B hi/lo: 1KB slot = 16 cols x 32 shorts; src k-granule XOR (col>>1)&3
#pragma unroll
    for (int half = 0; half < 2; ++half) {
      const unsigned short* Wt = half ? Btl : Bth;
      unsigned short* Bb = half ? &Bsl[buf][0] : &Bsh[buf][0];
#pragma unroll
      for (int i = 0; i < IPB; ++i) {
        int slot = wid * IPB + i;
        int c = slot * 16 + (lane >> 2);
        int gs = (lane & 3) ^ ((lane >> 3) & 3);   // (c>>1)&3 == (lane>>3)&3 here
        GLDS(Wt + (size_t)c * K + kb + gs * 8, Bb + slot * 512);
      }
    }
  };

  stage(0, 0);
  __syncthreads();

#pragma unroll 1
  for (int t = 0; t < NI; ++t) {
    int buf = t & 1;
    if (t + 1 < NI) stage(t + 1, buf ^ 1);

    // A fragments (un-swizzle), f32 -> bf16 hi/lo
    bf16x8 ah[MF], al[MF];
#pragma unroll
    for (int m = 0; m < MF; ++m) {
      int rt = wr * (MF * 16) + m * 16 + rlo;
      int p0 = (khi * 2) ^ (rt & 7), p1 = (khi * 2 + 1) ^ (rt & 7);
      f32x4 v0 = *reinterpret_cast<const f32x4*>(&As[buf][rt * 32 + p0 * 4]);
      f32x4 v1 = *reinterpret_cast<const f32x4*>(&As[buf][rt * 32 + p1 * 4]);
      float f[8] = {v0.x, v0.y, v0.z, v0.w, v1.x, v1.y, v1.z, v1.w};
#pragma unroll
      for (int i = 0; i < 8; ++i) {
        __bf16 hv = (__bf16)f[i];
        ah[m][i] = hv;
        al[m][i] = (__bf16)(f[i] - (float)hv);
      }
    }
    // B fragments (un-swizzle)
    short8 bh[4], bl[4];
#pragma unroll
    for (int n = 0; n < 4; ++n) {
      int c = wc * 64 + n * 16 + rlo;
      int perm = khi ^ ((c >> 1) & 3);
      bh[n] = *reinterpret_cast<const short8*>(&Bsh[buf][c * 32 + perm * 8]);
      bl[n] = *reinterpret_cast<const short8*>(&Bsl[buf][c * 32 + perm * 8]);
    }
#pragma unroll
    for (int m = 0; m < MF; ++m)
#pragma unroll
      for (int n = 0; n < 4; ++n) {
        acc[m][n] = __builtin_amdgcn_mfma_f32_16x16x32_bf16(
            ah[m], __builtin_bit_cast(bf16x8, bh[n]), acc[m][n], 0, 0, 0);
        acc[m][n] = __builtin_amdgcn_mfma_f32_16x16x32_bf16(
            al[m], __builtin_bit_cast(bf16x8, bh[n]), acc[m][n], 0, 0, 0);
        acc[m][n] = __builtin_amdgcn_mfma_f32_16x16x32_bf16(
            ah[m], __builtin_bit_cast(bf16x8, bl[n]), acc[m][n], 0, 0, 0);
      }
    __syncthreads();   // drains stage(t+1), frees buf for next overwrite
  }

  // C/D layout: col = lane&15, row = (lane>>4)*4 + reg  [m89-verified]
#pragma unroll
  for (int m = 0; m < MF; ++m)
#pragma unroll
    for (int j = 0; j < 4; ++j) {
      int row = row0 + m * 16 + khi * 4 + j;
      if (row < M) {
#pragma unroll
        for (int n = 0; n < 4; ++n)
          Y[(size_t)row * N + wc * 64 + n * 16 + rlo] = acc[m][n][j];
      }
    }
}

// ---------------- CSR aggregation: out[n] = bias + sum_e norm[e]*feat[rows[e]] ----------------
// F/4 lanes per node (float4 loads), 4-deep edge unroll for memory-level parallelism
template <int F, bool RELU>
__global__ void __launch_bounds__(256) agg_kernel(const float* __restrict__ feat,
                                                  const int* __restrict__ offs,
                                                  const int* __restrict__ rows,
                                                  const float* __restrict__ norms,
                                                  const float* __restrict__ bias,
                                                  float* __restrict__ out, int n) {
  constexpr int LPN = F / 4;        // lanes per node (32 for F=128, 16 for F=64)
  constexpr int NPW = 64 / LPN;     // nodes per wave (2 / 4)
  constexpr int NPB = 4 * NPW;      // nodes per 256-thread block
  int wid = threadIdx.x >> 6;
  int lane = threadIdx.x & 63;
  int node = blockIdx.x * NPB + wid * NPW + lane / LPN;
  int lf = (lane % LPN) * 4;        // feature offset
  if (node >= n) return;
  int e0 = offs[node], e1 = offs[node + 1];

  float4 acc = *reinterpret_cast<const float4*>(&bias[lf]);
  int e = e0;
  for (; e + 4 <= e1; e += 4) {
    int r0 = rows[e], r1 = rows[e + 1], r2 = rows[e + 2], r3 = rows[e + 3];
    float w0 = norms[e], w1 = norms[e + 1], w2 = norms[e + 2], w3 = norms[e + 3];
    float4 f0 = *reinterpret_cast<const float4*>(&feat[(size_t)r0 * F + lf]);
    float4 f1 = *reinterpret_cast<const float4*>(&feat[(size_t)r1 * F + lf]);
    float4 f2 = *reinterpret_cast<const float4*>(&feat[(size_t)r2 * F + lf]);
    float4 f3 = *reinterpret_cast<const float4*>(&feat[(size_t)r3 * F + lf]);
    acc.x = fmaf(w0, f0.x, acc.x); acc.y = fmaf(w0, f0.y, acc.y);
    acc.z = fmaf(w0, f0.z, acc.z); acc.w = fmaf(w0, f0.w, acc.w);
    acc.x = fmaf(w1, f1.x, acc.x); acc.y = fmaf(w1, f1.y, acc.y);
    acc.z = fmaf(w1, f1.z, acc.z); acc.w = fmaf(w1, f1.w, acc.w);
    acc.x = fmaf(w2, f2.x, acc.x); acc.y = fmaf(w2, f2.y, acc.y);
    acc.z = fmaf(w2, f2.z, acc.z); acc.w = fmaf(w2, f2.w, acc.w);
    acc.x = fmaf(w3, f3.x, acc.x); acc.y = fmaf(w3, f3.y, acc.y);
    acc.z = fmaf(w3, f3.z, acc.z); acc.w = fmaf(w3, f3.w, acc.w);
  }
  for (; e < e1; ++e) {
    int r = rows[e];
    float w = norms[e];
    float4 f = *reinterpret_cast<const float4*>(&feat[(size_t)r * F + lf]);
    acc.x = fmaf(w, f.x, acc.x); acc.y = fmaf(w, f.y, acc.y);
    acc.z = fmaf(w, f.z, acc.z); acc.w = fmaf(w, f.w, acc.w);
  }
  if (RELU) {
    acc.x = fmaxf(acc.x, 0.f); acc.y = fmaxf(acc.y, 0.f);
    acc.z = fmaxf(acc.z, 0.f); acc.w = fmaxf(acc.w, 0.f);
  }
  *reinterpret_cast<float4*>(&out[(size_t)node * F + lf]) = acc;
}

// ---------------- launch ----------------

extern "C" void kernel_launch(void* const* d_in, const int* in_sizes, int n_in,
                              void* d_out, int out_size, void* d_ws, size_t ws_size,
                              hipStream_t stream) {
  const float* x  = (const float*)d_in[0];
  const int*   ei = (const int*)d_in[1];     // [2, E] int
  const float* ew = (const float*)d_in[2];
  const float* W1 = (const float*)d_in[3];
  const float* b1 = (const float*)d_in[4];
  const float* W2 = (const float*)d_in[5];
  const float* b2 = (const float*)d_in[6];
  float* out = (float*)d_out;

  const int N = NNODES, E = NEDGES, EP = NNODES + NEDGES;

  char* p = (char*)d_ws;
  auto alloc = [&](size_t bytes) { char* r = p; p += (bytes + 255) & ~(size_t)255; return r; };
  float* deg    = (float*)alloc((size_t)N * 4);        // becomes dinv in-place
  int*   counts = (int*)  alloc((size_t)N * 4);
  int*   offs   = (int*)  alloc((size_t)(N + 1) * 4);
  int*   cursor = (int*)  alloc((size_t)N * 4);
  int*   rows   = (int*)  alloc((size_t)EP * 4);
  float* norms  = (float*)alloc((size_t)EP * 4);
  float* xw     = (float*)alloc((size_t)N * HID_C * 4); // layer1 pre-agg; reused as h2
  float* h      = (float*)alloc((size_t)N * HID_C * 4); // layer1 output
  unsigned short* W1th = (unsigned short*)alloc((size_t)IN_C * HID_C * 2);
  unsigned short* W1tl = (unsigned short*)alloc((size_t)IN_C * HID_C * 2);
  unsigned short* W2th = (unsigned short*)alloc((size_t)HID_C * OUT_C * 2);
  unsigned short* W2tl = (unsigned short*)alloc((size_t)HID_C * OUT_C * 2);

  init_kernel<<<(N + 255) / 256, 256, 0, stream>>>(deg, counts, N);
  deg_count_kernel<<<(E + 255) / 256, 256, 0, stream>>>(ei, ew, deg, counts, E);
  dinv_kernel<<<(N + 255) / 256, 256, 0, stream>>>(deg, N);
  scan_kernel<<<1, 1024, 0, stream>>>(counts, offs, N);
  copy_int_kernel<<<(N + 255) / 256, 256, 0, stream>>>(offs, cursor, N);
  fill_kernel<<<(EP + 255) / 256, 256, 0, stream>>>(ei, ew, deg, cursor, rows, norms, E, N);
  wsplit_kernel<<<(IN_C * HID_C + 255) / 256, 256, 0, stream>>>(W1, W1th, W1tl, IN_C, HID_C);
  wsplit_kernel<<<(HID_C * OUT_C + 255) / 256, 256, 0, stream>>>(W2, W2th, W2tl, HID_C, OUT_C);

  // layer 1: xw = x @ W1 ; h = relu(agg(xw) + b1)
  gemm_mfma_kernel<IN_C, HID_C, 2><<<(N + 63) / 64, 256, 0, stream>>>(x, W1th, W1tl, xw, N);
  agg_kernel<HID_C, true><<<(N + 7) / 8, 256, 0, stream>>>(xw, offs, rows, norms, b1, h, N);

  // layer 2: h2 = h @ W2 ; out = agg(h2) + b2
  gemm_mfma_kernel<HID_C, OUT_C, 1><<<(N + 63) / 64, 256, 0, stream>>>(h, W2th, W2tl, xw, N);
  agg_kernel<OUT_C, false><<<(N + 15) / 16, 256, 0, stream>>>(xw, offs, rows, norms, b2, out, N);
}

// Round 7
// 289.667 us; speedup vs baseline: 1.5352x; 1.2348x over previous
//
#include <hip/hip_runtime.h>

#define NNODES 50000
#define NEDGES 800000
#define IN_C   512
#define HID_C  128
#define OUT_C  64

typedef float  f32x4  __attribute__((ext_vector_type(4)));
typedef __bf16 bf16x8 __attribute__((ext_vector_type(8)));
typedef short  short8 __attribute__((ext_vector_type(8)));

#define GLDS(src, dst) \
  __builtin_amdgcn_global_load_lds( \
      (const __attribute__((address_space(1))) unsigned int*)(src), \
      (__attribute__((address_space(3))) unsigned int*)(dst), 16, 0, 0)

// ---------------- graph prep ----------------

__global__ void init_kernel(float* __restrict__ deg, int* __restrict__ counts, int n) {
  int i = blockIdx.x * blockDim.x + threadIdx.x;
  if (i < n) { deg[i] = 1.0f; counts[i] = 1; }   // self-loop: weight 1, one CSR slot
}

__global__ void deg_count_kernel(const int* __restrict__ ei, const float* __restrict__ ew,
                                 float* __restrict__ deg, int* __restrict__ counts, int nE) {
  int e = blockIdx.x * blockDim.x + threadIdx.x;
  if (e < nE) {
    int c = ei[nE + e];               // edge_index[1][e] (destination)
    atomicAdd(&deg[c], ew[e]);
    atomicAdd(&counts[c], 1);
  }
}

__global__ void dinv_kernel(float* __restrict__ deg, int n) {
  int i = blockIdx.x * blockDim.x + threadIdx.x;
  if (i < n) { float d = deg[i]; deg[i] = d > 0.f ? rsqrtf(d) : 0.f; }
}

// ---- parallel exclusive scan over counts[n] -> offs[0..n] (+cursor copy) ----
// 3 kernels, 1024 elements per block (256 threads x 4)

__global__ void __launch_bounds__(256) scan_partial_kernel(const int* __restrict__ counts,
                                                           int* __restrict__ bsum, int n) {
  int t = threadIdx.x;
  int i0 = blockIdx.x * 1024 + t * 4;
  int s = 0;
  if (i0 + 3 < n) {
    int4 v = *reinterpret_cast<const int4*>(&counts[i0]);
    s = v.x + v.y + v.z + v.w;
  } else {
#pragma unroll
    for (int j = 0; j < 4; ++j) if (i0 + j < n) s += counts[i0 + j];
  }
#pragma unroll
  for (int off = 32; off; off >>= 1) s += __shfl_down(s, off);
  __shared__ int ws[4];
  if ((t & 63) == 0) ws[t >> 6] = s;
  __syncthreads();
  if (t == 0) bsum[blockIdx.x] = ws[0] + ws[1] + ws[2] + ws[3];
}

__global__ void scan_bsum_kernel(int* __restrict__ bsum, int nb) {  // 1 block, 64 thr; nb<=64
  int lane = threadIdx.x;
  int orig = lane < nb ? bsum[lane] : 0;
  int v = orig;
#pragma unroll
  for (int off = 1; off < 64; off <<= 1) {
    int u = __shfl_up(v, off);
    if (lane >= off) v += u;
  }
  if (lane < nb) bsum[lane] = v - orig;   // exclusive
}

__global__ void __launch_bounds__(256) scan_final_kernel(const int* __restrict__ counts,
                                                         const int* __restrict__ bscan,
                                                         int* __restrict__ offs,
                                                         int* __restrict__ cursor, int n) {
  int t = threadIdx.x;
  int lane = t & 63, wid = t >> 6;
  int b = blockIdx.x;
  int i0 = b * 1024 + t * 4;
  int c[4];
#pragma unroll
  for (int j = 0; j < 4; ++j) c[j] = (i0 + j < n) ? counts[i0 + j] : 0;
  int s = c[0] + c[1] + c[2] + c[3];
  int v = s;
#pragma unroll
  for (int off = 1; off < 64; off <<= 1) {
    int u = __shfl_up(v, off);
    if (lane >= off) v += u;
  }
  __shared__ int wtot[4];
  if (lane == 63) wtot[wid] = v;
  __syncthreads();
  int wpre = 0;
#pragma unroll
  for (int w = 0; w < 4; ++w) if (w < wid) wpre += wtot[w];
  int p = bscan[b] + wpre + (v - s);     // exclusive prefix for this thread's first elem
#pragma unroll
  for (int j = 0; j < 4; ++j) {
    if (i0 + j < n) { offs[i0 + j] = p; cursor[i0 + j] = p; }
    p += c[j];
  }
  if (b == gridDim.x - 1 && t == 255)
    offs[n] = bscan[b] + wtot[0] + wtot[1] + wtot[2] + wtot[3];
}

// fill CSR (sorted by destination): rows[] = source node, norms[] = dinv[r]*w*dinv[c]
__global__ void fill_kernel(const int* __restrict__ ei, const float* __restrict__ ew,
                            const float* __restrict__ dinv, int* __restrict__ cursor,
                            int* __restrict__ rows, float* __restrict__ norms,
                            int nE, int nN) {
  int i = blockIdx.x * blockDim.x + threadIdx.x;
  if (i < nN) {                       // self-loop of node i
    float di = dinv[i];
    int pos = atomicAdd(&cursor[i], 1);
    rows[pos] = i;
    norms[pos] = di * di;
  } else if (i < nN + nE) {
    int e = i - nN;
    int r = ei[e], c = ei[nE + e];
    float w = dinv[r] * ew[e] * dinv[c];
    int pos = atomicAdd(&cursor[c], 1);
    rows[pos] = r;
    norms[pos] = w;
  }
}

// ---------------- W split+transpose: W[K][N] f32 -> Wt hi/lo [N][K] bf16 ----------------

__global__ void wsplit_kernel(const float* __restrict__ W, unsigned short* __restrict__ Th,
                              unsigned short* __restrict__ Tl, int K, int N) {
  int id = blockIdx.x * blockDim.x + threadIdx.x;
  if (id >= K * N) return;
  int k = id % K, n = id / K;           // consecutive id -> consecutive k -> coalesced writes
  float f = W[(size_t)k * N + n];
  __bf16 hb = (__bf16)f;
  float hf = (float)hb;
  __bf16 lb = (__bf16)(f - hf);
  Th[id] = __builtin_bit_cast(unsigned short, hb);
  Tl[id] = __builtin_bit_cast(unsigned short, lb);
}

// ---------------- split-bf16 MFMA GEMM, 2-phase LDS pipeline, A+B both staged ----------------
// Y[M,N] = X[M,K] @ W[K,N];  Y ~= Xh@Wh + Xl@Wh + Xh@Wl  (Xl@Wl dropped, ~2^-18)
// Per K-chunk (BK=32): A f32 tile AND B=W^T hi/lo bf16 tiles staged via global_load_lds
// (16B), double-buffered, one __syncthreads per chunk (T3-minimum skeleton).
// Swizzles (rule #21, both sides): A granule ^= (row&7); B k-granule ^= ((col>>1)&3),
// applied on the global SOURCE address (LDS dest is linear) and undone on ds_read.
// Both read patterns land 2-way bank-aliased = free (m136).
template <int K, int N, int MF>
__global__ void __launch_bounds__(256, 3) gemm_mfma_kernel(
    const float* __restrict__ X, const unsigned short* __restrict__ Bth,
    const unsigned short* __restrict__ Btl, float* __restrict__ Y, int M) {
  constexpr int NWC = N / 64;           // col wave-groups (2 for N=128, 1 for N=64)
  constexpr int NWR = 4 / NWC;          // row waves
  constexpr int BM = NWR * MF * 16;     // 64
  constexpr int BK = 32;
  constexpr int NI = K / BK;
  constexpr int IPA = BM / 32;          // A gld_lds per wave (BM*128B / 1KB / 4 waves)
  constexpr int IPB = N / 64;           // B gld_lds per wave per half (BK*N*2B / 1KB / 4)

  __shared__ float          As [2][BM * BK];   // 2 x 8KB
  __shared__ unsigned short Bsh[2][BK * N];    // 2 x (8KB | 4KB)
  __shared__ unsigned short Bsl[2][BK * N];

  int tid = threadIdx.x;
  int lane = tid & 63, wid = tid >> 6;
  int wr = wid / NWC, wc = wid % NWC;
  int row0blk = blockIdx.x * BM;
  int row0 = row0blk + wr * (MF * 16);
  int rlo = lane & 15;
  int khi = lane >> 4;

  f32x4 acc[MF][4] = {};

  // stage K-chunk t into buffer buf (whole block cooperates)
  auto stage = [&](int t, int buf) {
    int kb = t * BK;
    // A: 1KB slot = 8 rows x 32 floats; src granule XOR row&7 (slot*8 keeps row&7 = lane>>3)
#pragma unroll
    for (int i = 0; i < IPA; ++i) {
      int slot = wid * IPA + i;
      int rt = slot * 8 + (lane >> 3);
      int gr = row0blk + rt; gr = gr < M ? gr : M - 1;
      int gs = (lane & 7) ^ ((lane >> 3) & 7);
      GLDS(X + (size_t)gr * K + kb + gs * 4, &As[buf][slot * 256]);
    }
    // B hi/lo: 1KB slot = 16 cols x 32 shorts; src k-granule XOR (col>>1)&3
#pragma unroll
    for (int half = 0; half < 2; ++half) {
      const unsigned short* Wt = half ? Btl : Bth;
      unsigned short* Bb = half ? &Bsl[buf][0] : &Bsh[buf][0];
#pragma unroll
      for (int i = 0; i < IPB; ++i) {
        int slot = wid * IPB + i;
        int c = slot * 16 + (lane >> 2);
        int gs = (lane & 3) ^ ((lane >> 3) & 3);   // (c>>1)&3 == (lane>>3)&3 here
        GLDS(Wt + (size_t)c * K + kb + gs * 8, Bb + slot * 512);
      }
    }
  };

  stage(0, 0);
  __syncthreads();

#pragma unroll 1
  for (int t = 0; t < NI; ++t) {
    int buf = t & 1;
    if (t + 1 < NI) stage(t + 1, buf ^ 1);

    // A fragments (un-swizzle), f32 -> bf16 hi/lo
    bf16x8 ah[MF], al[MF];
#pragma unroll
    for (int m = 0; m < MF; ++m) {
      int rt = wr * (MF * 16) + m * 16 + rlo;
      int p0 = (khi * 2) ^ (rt & 7), p1 = (khi * 2 + 1) ^ (rt & 7);
      f32x4 v0 = *reinterpret_cast<const f32x4*>(&As[buf][rt * 32 + p0 * 4]);
      f32x4 v1 = *reinterpret_cast<const f32x4*>(&As[buf][rt * 32 + p1 * 4]);
      float f[8] = {v0.x, v0.y, v0.z, v0.w, v1.x, v1.y, v1.z, v1.w};
#pragma unroll
      for (int i = 0; i < 8; ++i) {
        __bf16 hv = (__bf16)f[i];
        ah[m][i] = hv;
        al[m][i] = (__bf16)(f[i] - (float)hv);
      }
    }
    // B fragments (un-swizzle)
    short8 bh[4], bl[4];
#pragma unroll
    for (int n = 0; n < 4; ++n) {
      int c = wc * 64 + n * 16 + rlo;
      int perm = khi ^ ((c >> 1) & 3);
      bh[n] = *reinterpret_cast<const short8*>(&Bsh[buf][c * 32 + perm * 8]);
      bl[n] = *reinterpret_cast<const short8*>(&Bsl[buf][c * 32 + perm * 8]);
    }
#pragma unroll
    for (int m = 0; m < MF; ++m)
#pragma unroll
      for (int n = 0; n < 4; ++n) {
        acc[m][n] = __builtin_amdgcn_mfma_f32_16x16x32_bf16(
            ah[m], __builtin_bit_cast(bf16x8, bh[n]), acc[m][n], 0, 0, 0);
        acc[m][n] = __builtin_amdgcn_mfma_f32_16x16x32_bf16(
            al[m], __builtin_bit_cast(bf16x8, bh[n]), acc[m][n], 0, 0, 0);
        acc[m][n] = __builtin_amdgcn_mfma_f32_16x16x32_bf16(
            ah[m], __builtin_bit_cast(bf16x8, bl[n]), acc[m][n], 0, 0, 0);
      }
    __syncthreads();   // drains stage(t+1), frees buf for next overwrite
  }

  // C/D layout: col = lane&15, row = (lane>>4)*4 + reg  [m89-verified]
#pragma unroll
  for (int m = 0; m < MF; ++m)
#pragma unroll
    for (int j = 0; j < 4; ++j) {
      int row = row0 + m * 16 + khi * 4 + j;
      if (row < M) {
#pragma unroll
        for (int n = 0; n < 4; ++n)
          Y[(size_t)row * N + wc * 64 + n * 16 + rlo] = acc[m][n][j];
      }
    }
}

// ---------------- CSR aggregation: out[n] = bias + sum_e norm[e]*feat[rows[e]] ----------------
// F/4 lanes per node (float4 loads), 4-deep edge unroll for memory-level parallelism
template <int F, bool RELU>
__global__ void __launch_bounds__(256) agg_kernel(const float* __restrict__ feat,
                                                  const int* __restrict__ offs,
                                                  const int* __restrict__ rows,
                                                  const float* __restrict__ norms,
                                                  const float* __restrict__ bias,
                                                  float* __restrict__ out, int n) {
  constexpr int LPN = F / 4;        // lanes per node (32 for F=128, 16 for F=64)
  constexpr int NPW = 64 / LPN;     // nodes per wave (2 / 4)
  constexpr int NPB = 4 * NPW;      // nodes per 256-thread block
  int wid = threadIdx.x >> 6;
  int lane = threadIdx.x & 63;
  int node = blockIdx.x * NPB + wid * NPW + lane / LPN;
  int lf = (lane % LPN) * 4;        // feature offset
  if (node >= n) return;
  int e0 = offs[node], e1 = offs[node + 1];

  float4 acc = *reinterpret_cast<const float4*>(&bias[lf]);
  int e = e0;
  for (; e + 4 <= e1; e += 4) {
    int r0 = rows[e], r1 = rows[e + 1], r2 = rows[e + 2], r3 = rows[e + 3];
    float w0 = norms[e], w1 = norms[e + 1], w2 = norms[e + 2], w3 = norms[e + 3];
    float4 f0 = *reinterpret_cast<const float4*>(&feat[(size_t)r0 * F + lf]);
    float4 f1 = *reinterpret_cast<const float4*>(&feat[(size_t)r1 * F + lf]);
    float4 f2 = *reinterpret_cast<const float4*>(&feat[(size_t)r2 * F + lf]);
    float4 f3 = *reinterpret_cast<const float4*>(&feat[(size_t)r3 * F + lf]);
    acc.x = fmaf(w0, f0.x, acc.x); acc.y = fmaf(w0, f0.y, acc.y);
    acc.z = fmaf(w0, f0.z, acc.z); acc.w = fmaf(w0, f0.w, acc.w);
    acc.x = fmaf(w1, f1.x, acc.x); acc.y = fmaf(w1, f1.y, acc.y);
    acc.z = fmaf(w1, f1.z, acc.z); acc.w = fmaf(w1, f1.w, acc.w);
    acc.x = fmaf(w2, f2.x, acc.x); acc.y = fmaf(w2, f2.y, acc.y);
    acc.z = fmaf(w2, f2.z, acc.z); acc.w = fmaf(w2, f2.w, acc.w);
    acc.x = fmaf(w3, f3.x, acc.x); acc.y = fmaf(w3, f3.y, acc.y);
    acc.z = fmaf(w3, f3.z, acc.z); acc.w = fmaf(w3, f3.w, acc.w);
  }
  for (; e < e1; ++e) {
    int r = rows[e];
    float w = norms[e];
    float4 f = *reinterpret_cast<const float4*>(&feat[(size_t)r * F + lf]);
    acc.x = fmaf(w, f.x, acc.x); acc.y = fmaf(w, f.y, acc.y);
    acc.z = fmaf(w, f.z, acc.z); acc.w = fmaf(w, f.w, acc.w);
  }
  if (RELU) {
    acc.x = fmaxf(acc.x, 0.f); acc.y = fmaxf(acc.y, 0.f);
    acc.z = fmaxf(acc.z, 0.f); acc.w = fmaxf(acc.w, 0.f);
  }
  *reinterpret_cast<float4*>(&out[(size_t)node * F + lf]) = acc;
}

// ---------------- launch ----------------

extern "C" void kernel_launch(void* const* d_in, const int* in_sizes, int n_in,
                              void* d_out, int out_size, void* d_ws, size_t ws_size,
                              hipStream_t stream) {
  const float* x  = (const float*)d_in[0];
  const int*   ei = (const int*)d_in[1];     // [2, E] int
  const float* ew = (const float*)d_in[2];
  const float* W1 = (const float*)d_in[3];
  const float* b1 = (const float*)d_in[4];
  const float* W2 = (const float*)d_in[5];
  const float* b2 = (const float*)d_in[6];
  float* out = (float*)d_out;

  const int N = NNODES, E = NEDGES, EP = NNODES + NEDGES;
  const int NB = (N + 1023) / 1024;          // scan blocks (49)

  char* p = (char*)d_ws;
  auto alloc = [&](size_t bytes) { char* r = p; p += (bytes + 255) & ~(size_t)255; return r; };
  float* deg    = (float*)alloc((size_t)N * 4);        // becomes dinv in-place
  int*   counts = (int*)  alloc((size_t)N * 4);
  int*   offs   = (int*)  alloc((size_t)(N + 1) * 4);
  int*   cursor = (int*)  alloc((size_t)N * 4);
  int*   bsum   = (int*)  alloc((size_t)64 * 4);
  int*   rows   = (int*)  alloc((size_t)EP * 4);
  float* norms  = (float*)alloc((size_t)EP * 4);
  float* xw     = (float*)alloc((size_t)N * HID_C * 4); // layer1 pre-agg; reused as h2
  float* h      = (float*)alloc((size_t)N * HID_C * 4); // layer1 output
  unsigned short* W1th = (unsigned short*)alloc((size_t)IN_C * HID_C * 2);
  unsigned short* W1tl = (unsigned short*)alloc((size_t)IN_C * HID_C * 2);
  unsigned short* W2th = (unsigned short*)alloc((size_t)HID_C * OUT_C * 2);
  unsigned short* W2tl = (unsigned short*)alloc((size_t)HID_C * OUT_C * 2);

  init_kernel<<<(N + 255) / 256, 256, 0, stream>>>(deg, counts, N);
  deg_count_kernel<<<(E + 255) / 256, 256, 0, stream>>>(ei, ew, deg, counts, E);
  dinv_kernel<<<(N + 255) / 256, 256, 0, stream>>>(deg, N);
  scan_partial_kernel<<<NB, 256, 0, stream>>>(counts, bsum, N);
  scan_bsum_kernel<<<1, 64, 0, stream>>>(bsum, NB);
  scan_final_kernel<<<NB, 256, 0, stream>>>(counts, bsum, offs, cursor, N);
  fill_kernel<<<(EP + 255) / 256, 256, 0, stream>>>(ei, ew, deg, cursor, rows, norms, E, N);
  wsplit_kernel<<<(IN_C * HID_C + 255) / 256, 256, 0, stream>>>(W1, W1th, W1tl, IN_C, HID_C);
  wsplit_kernel<<<(HID_C * OUT_C + 255) / 256, 256, 0, stream>>>(W2, W2th, W2tl, HID_C, OUT_C);

  // layer 1: xw = x @ W1 ; h = relu(agg(xw) + b1)
  gemm_mfma_kernel<IN_C, HID_C, 2><<<(N + 63) / 64, 256, 0, stream>>>(x, W1th, W1tl, xw, N);
  agg_kernel<HID_C, true><<<(N + 7) / 8, 256, 0, stream>>>(xw, offs, rows, norms, b1, h, N);

  // layer 2: h2 = h @ W2 ; out = agg(h2) + b2
  gemm_mfma_kernel<HID_C, OUT_C, 1><<<(N + 63) / 64, 256, 0, stream>>>(h, W2th, W2tl, xw, N);
  agg_kernel<OUT_C, false><<<(N + 15) / 16, 256, 0, stream>>>(xw, offs, rows, norms, b2, out, N);
}

// Round 8
// 232.990 us; speedup vs baseline: 1.9086x; 1.2433x over previous
//
#include <hip/hip_runtime.h>

#define NNODES 50000
#define NEDGES 800000
#define IN_C   512
#define HID_C  128
#define OUT_C  64

typedef float  f32x4  __attribute__((ext_vector_type(4)));
typedef __bf16 bf16x8 __attribute__((ext_vector_type(8)));
typedef short  short8 __attribute__((ext_vector_type(8)));

#define GLDS(src, dst) \
  __builtin_amdgcn_global_load_lds( \
      (const __attribute__((address_space(1))) unsigned int*)(src), \
      (__attribute__((address_space(3))) unsigned int*)(dst), 16, 0, 0)

// ---------------- graph prep ----------------
// deg+count packed in ONE u64 per node: bits[0:20)=count, bits[20:64)=deg in 2^-24 units.
// One node per 32B sector (stride 4 u64) to spread atomic contention.

__global__ void deg_count_kernel(const int* __restrict__ ei, const float* __restrict__ ew,
                                 unsigned long long* __restrict__ packed, int nE) {
  int e = blockIdx.x * blockDim.x + threadIdx.x;
  if (e < nE) {
    int c = ei[nE + e];               // edge_index[1][e] (destination)
    unsigned int fx = __float2uint_rn(ew[e] * 16777216.0f);   // ew in [0,1)
    atomicAdd(&packed[(size_t)c * 4], ((unsigned long long)fx << 20) | 1ULL);
  }
}

// decode packed -> dinv (rsqrt) + dense counts (for scan)
__global__ void decode_kernel(const unsigned long long* __restrict__ packed,
                              float* __restrict__ dinv, int* __restrict__ counts, int n) {
  int i = blockIdx.x * blockDim.x + threadIdx.x;
  if (i < n) {
    unsigned long long p = packed[(size_t)i * 4];
    counts[i] = (int)(p & 0xFFFFFULL) + 1;                     // + self-loop slot
    float deg = (float)((double)(p >> 20) * (1.0 / 16777216.0) + 1.0);  // + self-loop w=1
    dinv[i] = rsqrtf(deg);                                     // deg >= 1 always
  }
}

// ---- parallel exclusive scan over counts[n] -> offs[0..n] (+cursor=offs+1, 32B-strided) ----

__global__ void __launch_bounds__(256) scan_partial_kernel(const int* __restrict__ counts,
                                                           int* __restrict__ bsum, int n) {
  int t = threadIdx.x;
  int i0 = blockIdx.x * 1024 + t * 4;
  int s = 0;
  if (i0 + 3 < n) {
    int4 v = *reinterpret_cast<const int4*>(&counts[i0]);
    s = v.x + v.y + v.z + v.w;
  } else {
#pragma unroll
    for (int j = 0; j < 4; ++j) if (i0 + j < n) s += counts[i0 + j];
  }
#pragma unroll
  for (int off = 32; off; off >>= 1) s += __shfl_down(s, off);
  __shared__ int ws[4];
  if ((t & 63) == 0) ws[t >> 6] = s;
  __syncthreads();
  if (t == 0) bsum[blockIdx.x] = ws[0] + ws[1] + ws[2] + ws[3];
}

__global__ void scan_bsum_kernel(int* __restrict__ bsum, int nb) {  // 1 block, 64 thr; nb<=64
  int lane = threadIdx.x;
  int orig = lane < nb ? bsum[lane] : 0;
  int v = orig;
#pragma unroll
  for (int off = 1; off < 64; off <<= 1) {
    int u = __shfl_up(v, off);
    if (lane >= off) v += u;
  }
  if (lane < nb) bsum[lane] = v - orig;   // exclusive
}

__global__ void __launch_bounds__(256) scan_final_kernel(const int* __restrict__ counts,
                                                         const int* __restrict__ bscan,
                                                         int* __restrict__ offs,
                                                         int* __restrict__ cursor, int n) {
  int t = threadIdx.x;
  int lane = t & 63, wid = t >> 6;
  int b = blockIdx.x;
  int i0 = b * 1024 + t * 4;
  int c[4];
#pragma unroll
  for (int j = 0; j < 4; ++j) c[j] = (i0 + j < n) ? counts[i0 + j] : 0;
  int s = c[0] + c[1] + c[2] + c[3];
  int v = s;
#pragma unroll
  for (int off = 1; off < 64; off <<= 1) {
    int u = __shfl_up(v, off);
    if (lane >= off) v += u;
  }
  __shared__ int wtot[4];
  if (lane == 63) wtot[wid] = v;
  __syncthreads();
  int wpre = 0;
#pragma unroll
  for (int w = 0; w < 4; ++w) if (w < wid) wpre += wtot[w];
  int p = bscan[b] + wpre + (v - s);     // exclusive prefix for this thread's first elem
#pragma unroll
  for (int j = 0; j < 4; ++j) {
    if (i0 + j < n) {
      offs[i0 + j] = p;
      cursor[(size_t)(i0 + j) * 8] = p + 1;   // slot p reserved for self-loop
    }
    p += c[j];
  }
  if (b == gridDim.x - 1 && t == 255)
    offs[n] = bscan[b] + wtot[0] + wtot[1] + wtot[2] + wtot[3];
}

// fill CSR (sorted by destination): edges[pos] = {src row, norm}
// self-loop goes atomic-free to slot offs[i]; dynamic edges via padded cursor atomics
__global__ void fill_kernel(const int* __restrict__ ei, const float* __restrict__ ew,
                            const float* __restrict__ dinv, const int* __restrict__ offs,
                            int* __restrict__ cursor, int2* __restrict__ edges,
                            int nE, int nN) {
  int i = blockIdx.x * blockDim.x + threadIdx.x;
  if (i < nN) {                       // self-loop of node i
    float di = dinv[i];
    edges[offs[i]] = make_int2(i, __float_as_int(di * di));
  } else if (i < nN + nE) {
    int e = i - nN;
    int r = ei[e], c = ei[nE + e];
    float w = dinv[r] * ew[e] * dinv[c];
    int pos = atomicAdd(&cursor[(size_t)c * 8], 1);
    edges[pos] = make_int2(r, __float_as_int(w));
  }
}

// ---------------- W split+transpose: W[K][N] f32 -> Wt hi/lo [N][K] bf16 ----------------

__global__ void wsplit_kernel(const float* __restrict__ W, unsigned short* __restrict__ Th,
                              unsigned short* __restrict__ Tl, int K, int N) {
  int id = blockIdx.x * blockDim.x + threadIdx.x;
  if (id >= K * N) return;
  int k = id % K, n = id / K;           // consecutive id -> consecutive k -> coalesced writes
  float f = W[(size_t)k * N + n];
  __bf16 hb = (__bf16)f;
  float hf = (float)hb;
  __bf16 lb = (__bf16)(f - hf);
  Th[id] = __builtin_bit_cast(unsigned short, hb);
  Tl[id] = __builtin_bit_cast(unsigned short, lb);
}

// ---------------- split-bf16 MFMA GEMM, 2-phase LDS pipeline, A+B both staged ----------------
// Y[M,N] = X[M,K] @ W[K,N];  Y ~= Xh@Wh + Xl@Wh + Xh@Wl  (Xl@Wl dropped, ~2^-18)
// Per K-chunk (BK=32): A f32 tile AND B=W^T hi/lo bf16 tiles staged via global_load_lds
// (16B), double-buffered, one __syncthreads per chunk (T3-minimum skeleton).
// Swizzles (rule #21, both sides): A granule ^= (row&7); B k-granule ^= ((col>>1)&3),
// applied on the global SOURCE address (LDS dest is linear) and undone on ds_read.
template <int K, int N, int MF>
__global__ void __launch_bounds__(256, 3) gemm_mfma_kernel(
    const float* __restrict__ X, const unsigned short* __restrict__ Bth,
    const unsigned short* __restrict__ Btl, float* __restrict__ Y, int M) {
  constexpr int NWC = N / 64;           // col wave-groups (2 for N=128, 1 for N=64)
  constexpr int NWR = 4 / NWC;          // row waves
  constexpr int BM = NWR * MF * 16;     // 64
  constexpr int BK = 32;
  constexpr int NI = K / BK;
  constexpr int IPA = BM / 32;          // A gld_lds per wave
  constexpr int IPB = N / 64;           // B gld_lds per wave per half

  __shared__ float          As [2][BM * BK];
  __shared__ unsigned short Bsh[2][BK * N];
  __shared__ unsigned short Bsl[2][BK * N];

  int tid = threadIdx.x;
  int lane = tid & 63, wid = tid >> 6;
  int wr = wid / NWC, wc = wid % NWC;
  int row0blk = blockIdx.x * BM;
  int row0 = row0blk + wr * (MF * 16);
  int rlo = lane & 15;
  int khi = lane >> 4;

  f32x4 acc[MF][4] = {};

  auto stage = [&](int t, int buf) {
    int kb = t * BK;
#pragma unroll
    for (int i = 0; i < IPA; ++i) {
      int slot = wid * IPA + i;
      int rt = slot * 8 + (lane >> 3);
      int gr = row0blk + rt; gr = gr < M ? gr : M - 1;
      int gs = (lane & 7) ^ ((lane >> 3) & 7);
      GLDS(X + (size_t)gr * K + kb + gs * 4, &As[buf][slot * 256]);
    }
#pragma unroll
    for (int half = 0; half < 2; ++half) {
      const unsigned short* Wt = half ? Btl : Bth;
      unsigned short* Bb = half ? &Bsl[buf][0] : &Bsh[buf][0];
#pragma unroll
      for (int i = 0; i < IPB; ++i) {
        int slot = wid * IPB + i;
        int c = slot * 16 + (lane >> 2);
        int gs = (lane & 3) ^ ((lane >> 3) & 3);
        GLDS(Wt + (size_t)c * K + kb + gs * 8, Bb + slot * 512);
      }
    }
  };

  stage(0, 0);
  __syncthreads();

#pragma unroll 1
  for (int t = 0; t < NI; ++t) {
    int buf = t & 1;
    if (t + 1 < NI) stage(t + 1, buf ^ 1);

    bf16x8 ah[MF], al[MF];
#pragma unroll
    for (int m = 0; m < MF; ++m) {
      int rt = wr * (MF * 16) + m * 16 + rlo;
      int p0 = (khi * 2) ^ (rt & 7), p1 = (khi * 2 + 1) ^ (rt & 7);
      f32x4 v0 = *reinterpret_cast<const f32x4*>(&As[buf][rt * 32 + p0 * 4]);
      f32x4 v1 = *reinterpret_cast<const f32x4*>(&As[buf][rt * 32 + p1 * 4]);
      float f[8] = {v0.x, v0.y, v0.z, v0.w, v1.x, v1.y, v1.z, v1.w};
#pragma unroll
      for (int i = 0; i < 8; ++i) {
        __bf16 hv = (__bf16)f[i];
        ah[m][i] = hv;
        al[m][i] = (__bf16)(f[i] - (float)hv);
      }
    }
    short8 bh[4], bl[4];
#pragma unroll
    for (int n = 0; n < 4; ++n) {
      int c = wc * 64 + n * 16 + rlo;
      int perm = khi ^ ((c >> 1) & 3);
      bh[n] = *reinterpret_cast<const short8*>(&Bsh[buf][c * 32 + perm * 8]);
      bl[n] = *reinterpret_cast<const short8*>(&Bsl[buf][c * 32 + perm * 8]);
    }
#pragma unroll
    for (int m = 0; m < MF; ++m)
#pragma unroll
      for (int n = 0; n < 4; ++n) {
        acc[m][n] = __builtin_amdgcn_mfma_f32_16x16x32_bf16(
            ah[m], __builtin_bit_cast(bf16x8, bh[n]), acc[m][n], 0, 0, 0);
        acc[m][n] = __builtin_amdgcn_mfma_f32_16x16x32_bf16(
            al[m], __builtin_bit_cast(bf16x8, bh[n]), acc[m][n], 0, 0, 0);
        acc[m][n] = __builtin_amdgcn_mfma_f32_16x16x32_bf16(
            ah[m], __builtin_bit_cast(bf16x8, bl[n]), acc[m][n], 0, 0, 0);
      }
    __syncthreads();
  }

  // C/D layout: col = lane&15, row = (lane>>4)*4 + reg  [m89-verified]
#pragma unroll
  for (int m = 0; m < MF; ++m)
#pragma unroll
    for (int j = 0; j < 4; ++j) {
      int row = row0 + m * 16 + khi * 4 + j;
      if (row < M) {
#pragma unroll
        for (int n = 0; n < 4; ++n)
          Y[(size_t)row * N + wc * 64 + n * 16 + rlo] = acc[m][n][j];
      }
    }
}

// ---------------- CSR aggregation: out[n] = bias + sum_e w*feat[row] over edge records ----
// F/4 lanes per node (float4 loads), 4-deep edge unroll; edge = {row, norm} in one int2
template <int F, bool RELU>
__global__ void __launch_bounds__(256) agg_kernel(const float* __restrict__ feat,
                                                  const int* __restrict__ offs,
                                                  const int2* __restrict__ edges,
                                                  const float* __restrict__ bias,
                                                  float* __restrict__ out, int n) {
  constexpr int LPN = F / 4;        // lanes per node (32 for F=128, 16 for F=64)
  constexpr int NPW = 64 / LPN;     // nodes per wave (2 / 4)
  constexpr int NPB = 4 * NPW;      // nodes per 256-thread block
  int wid = threadIdx.x >> 6;
  int lane = threadIdx.x & 63;
  int node = blockIdx.x * NPB + wid * NPW + lane / LPN;
  int lf = (lane % LPN) * 4;        // feature offset
  if (node >= n) return;
  int e0 = offs[node], e1 = offs[node + 1];

  float4 acc = *reinterpret_cast<const float4*>(&bias[lf]);
  int e = e0;
  for (; e + 4 <= e1; e += 4) {
    int2 q0 = edges[e], q1 = edges[e + 1], q2 = edges[e + 2], q3 = edges[e + 3];
    float w0 = __int_as_float(q0.y), w1 = __int_as_float(q1.y);
    float w2 = __int_as_float(q2.y), w3 = __int_as_float(q3.y);
    float4 f0 = *reinterpret_cast<const float4*>(&feat[(size_t)q0.x * F + lf]);
    float4 f1 = *reinterpret_cast<const float4*>(&feat[(size_t)q1.x * F + lf]);
    float4 f2 = *reinterpret_cast<const float4*>(&feat[(size_t)q2.x * F + lf]);
    float4 f3 = *reinterpret_cast<const float4*>(&feat[(size_t)q3.x * F + lf]);
    acc.x = fmaf(w0, f0.x, acc.x); acc.y = fmaf(w0, f0.y, acc.y);
    acc.z = fmaf(w0, f0.z, acc.z); acc.w = fmaf(w0, f0.w, acc.w);
    acc.x = fmaf(w1, f1.x, acc.x); acc.y = fmaf(w1, f1.y, acc.y);
    acc.z = fmaf(w1, f1.z, acc.z); acc.w = fmaf(w1, f1.w, acc.w);
    acc.x = fmaf(w2, f2.x, acc.x); acc.y = fmaf(w2, f2.y, acc.y);
    acc.z = fmaf(w2, f2.z, acc.z); acc.w = fmaf(w2, f2.w, acc.w);
    acc.x = fmaf(w3, f3.x, acc.x); acc.y = fmaf(w3, f3.y, acc.y);
    acc.z = fmaf(w3, f3.z, acc.z); acc.w = fmaf(w3, f3.w, acc.w);
  }
  for (; e < e1; ++e) {
    int2 q = edges[e];
    float w = __int_as_float(q.y);
    float4 f = *reinterpret_cast<const float4*>(&feat[(size_t)q.x * F + lf]);
    acc.x = fmaf(w, f.x, acc.x); acc.y = fmaf(w, f.y, acc.y);
    acc.z = fmaf(w, f.z, acc.z); acc.w = fmaf(w, f.w, acc.w);
  }
  if (RELU) {
    acc.x = fmaxf(acc.x, 0.f); acc.y = fmaxf(acc.y, 0.f);
    acc.z = fmaxf(acc.z, 0.f); acc.w = fmaxf(acc.w, 0.f);
  }
  *reinterpret_cast<float4*>(&out[(size_t)node * F + lf]) = acc;
}

// ---------------- launch ----------------

extern "C" void kernel_launch(void* const* d_in, const int* in_sizes, int n_in,
                              void* d_out, int out_size, void* d_ws, size_t ws_size,
                              hipStream_t stream) {
  const float* x  = (const float*)d_in[0];
  const int*   ei = (const int*)d_in[1];     // [2, E] int
  const float* ew = (const float*)d_in[2];
  const float* W1 = (const float*)d_in[3];
  const float* b1 = (const float*)d_in[4];
  const float* W2 = (const float*)d_in[5];
  const float* b2 = (const float*)d_in[6];
  float* out = (float*)d_out;

  const int N = NNODES, E = NEDGES, EP = NNODES + NEDGES;
  const int NB = (N + 1023) / 1024;          // scan blocks (49)

  char* p = (char*)d_ws;
  auto alloc = [&](size_t bytes) { char* r = p; p += (bytes + 255) & ~(size_t)255; return r; };
  unsigned long long* packed = (unsigned long long*)alloc((size_t)N * 32); // 1/32B sector
  float* dinv   = (float*)alloc((size_t)N * 4);
  int*   counts = (int*)  alloc((size_t)N * 4);
  int*   offs   = (int*)  alloc((size_t)(N + 1) * 4);
  int*   cursor = (int*)  alloc((size_t)N * 32);       // 1 counter per 32B sector
  int*   bsum   = (int*)  alloc((size_t)64 * 4);
  int2*  edges  = (int2*) alloc((size_t)EP * 8);       // {row, norm}
  float* xw     = (float*)alloc((size_t)N * HID_C * 4); // layer1 pre-agg; reused as h2
  float* h      = (float*)alloc((size_t)N * HID_C * 4); // layer1 output
  unsigned short* W1th = (unsigned short*)alloc((size_t)IN_C * HID_C * 2);
  unsigned short* W1tl = (unsigned short*)alloc((size_t)IN_C * HID_C * 2);
  unsigned short* W2th = (unsigned short*)alloc((size_t)HID_C * OUT_C * 2);
  unsigned short* W2tl = (unsigned short*)alloc((size_t)HID_C * OUT_C * 2);

  hipMemsetAsync(packed, 0, (size_t)N * 32, stream);
  deg_count_kernel<<<(E + 255) / 256, 256, 0, stream>>>(ei, ew, packed, E);
  decode_kernel<<<(N + 255) / 256, 256, 0, stream>>>(packed, dinv, counts, N);
  scan_partial_kernel<<<NB, 256, 0, stream>>>(counts, bsum, N);
  scan_bsum_kernel<<<1, 64, 0, stream>>>(bsum, NB);
  scan_final_kernel<<<NB, 256, 0, stream>>>(counts, bsum, offs, cursor, N);
  fill_kernel<<<(EP + 255) / 256, 256, 0, stream>>>(ei, ew, dinv, offs, cursor, edges, E, N);
  wsplit_kernel<<<(IN_C * HID_C + 255) / 256, 256, 0, stream>>>(W1, W1th, W1tl, IN_C, HID_C);
  wsplit_kernel<<<(HID_C * OUT_C + 255) / 256, 256, 0, stream>>>(W2, W2th, W2tl, HID_C, OUT_C);

  // layer 1: xw = x @ W1 ; h = relu(agg(xw) + b1)
  gemm_mfma_kernel<IN_C, HID_C, 2><<<(N + 63) / 64, 256, 0, stream>>>(x, W1th, W1tl, xw, N);
  agg_kernel<HID_C, true><<<(N + 7) / 8, 256, 0, stream>>>(xw, offs, edges, b1, h, N);

  // layer 2: h2 = h @ W2 ; out = agg(h2) + b2
  gemm_mfma_kernel<HID_C, OUT_C, 1><<<(N + 63) / 64, 256, 0, stream>>>(h, W2th, W2tl, xw, N);
  agg_kernel<OUT_C, false><<<(N + 15) / 16, 256, 0, stream>>>(xw, offs, edges, b2, out, N);
}

// Round 9
// 225.281 us; speedup vs baseline: 1.9739x; 1.0342x over previous
//
#include <hip/hip_runtime.h>

#define NNODES 50000
#define NEDGES 800000
#define IN_C   512
#define HID_C  128
#define OUT_C  64

typedef float  f32x4  __attribute__((ext_vector_type(4)));
typedef __bf16 bf16x8 __attribute__((ext_vector_type(8)));
typedef short  short8 __attribute__((ext_vector_type(8)));

#define GLDS(src, dst) \
  __builtin_amdgcn_global_load_lds( \
      (const __attribute__((address_space(1))) unsigned int*)(src), \
      (__attribute__((address_space(3))) unsigned int*)(dst), 16, 0, 0)

// ---------------- graph prep ----------------
// deg+count packed in ONE u64 per node: bits[0:20)=count, bits[20:64)=deg in 2^-24 units.
// One node per 32B sector (stride 4 u64) to spread atomic contention.

__global__ void deg_count_kernel(const int* __restrict__ ei, const float* __restrict__ ew,
                                 unsigned long long* __restrict__ packed, int nE) {
  int e = blockIdx.x * blockDim.x + threadIdx.x;
  if (e < nE) {
    int c = ei[nE + e];               // edge_index[1][e] (destination)
    unsigned int fx = __float2uint_rn(ew[e] * 16777216.0f);   // ew in [0,1)
    atomicAdd(&packed[(size_t)c * 4], ((unsigned long long)fx << 20) | 1ULL);
  }
}

// decode packed -> dinv (rsqrt) + dense counts (for scan)
__global__ void decode_kernel(const unsigned long long* __restrict__ packed,
                              float* __restrict__ dinv, int* __restrict__ counts, int n) {
  int i = blockIdx.x * blockDim.x + threadIdx.x;
  if (i < n) {
    unsigned long long p = packed[(size_t)i * 4];
    counts[i] = (int)(p & 0xFFFFFULL) + 1;                     // + self-loop slot
    float deg = (float)((double)(p >> 20) * (1.0 / 16777216.0) + 1.0);  // + self-loop w=1
    dinv[i] = rsqrtf(deg);                                     // deg >= 1 always
  }
}

// ---- parallel exclusive scan over counts[n] -> offs[0..n] (+cursor=offs+1, 32B-strided) ----

__global__ void __launch_bounds__(256) scan_partial_kernel(const int* __restrict__ counts,
                                                           int* __restrict__ bsum, int n) {
  int t = threadIdx.x;
  int i0 = blockIdx.x * 1024 + t * 4;
  int s = 0;
  if (i0 + 3 < n) {
    int4 v = *reinterpret_cast<const int4*>(&counts[i0]);
    s = v.x + v.y + v.z + v.w;
  } else {
#pragma unroll
    for (int j = 0; j < 4; ++j) if (i0 + j < n) s += counts[i0 + j];
  }
#pragma unroll
  for (int off = 32; off; off >>= 1) s += __shfl_down(s, off);
  __shared__ int ws[4];
  if ((t & 63) == 0) ws[t >> 6] = s;
  __syncthreads();
  if (t == 0) bsum[blockIdx.x] = ws[0] + ws[1] + ws[2] + ws[3];
}

__global__ void scan_bsum_kernel(int* __restrict__ bsum, int nb) {  // 1 block, 64 thr; nb<=64
  int lane = threadIdx.x;
  int orig = lane < nb ? bsum[lane] : 0;
  int v = orig;
#pragma unroll
  for (int off = 1; off < 64; off <<= 1) {
    int u = __shfl_up(v, off);
    if (lane >= off) v += u;
  }
  if (lane < nb) bsum[lane] = v - orig;   // exclusive
}

__global__ void __launch_bounds__(256) scan_final_kernel(const int* __restrict__ counts,
                                                         const int* __restrict__ bscan,
                                                         int* __restrict__ offs,
                                                         int* __restrict__ cursor, int n) {
  int t = threadIdx.x;
  int lane = t & 63, wid = t >> 6;
  int b = blockIdx.x;
  int i0 = b * 1024 + t * 4;
  int c[4];
#pragma unroll
  for (int j = 0; j < 4; ++j) c[j] = (i0 + j < n) ? counts[i0 + j] : 0;
  int s = c[0] + c[1] + c[2] + c[3];
  int v = s;
#pragma unroll
  for (int off = 1; off < 64; off <<= 1) {
    int u = __shfl_up(v, off);
    if (lane >= off) v += u;
  }
  __shared__ int wtot[4];
  if (lane == 63) wtot[wid] = v;
  __syncthreads();
  int wpre = 0;
#pragma unroll
  for (int w = 0; w < 4; ++w) if (w < wid) wpre += wtot[w];
  int p = bscan[b] + wpre + (v - s);     // exclusive prefix for this thread's first elem
#pragma unroll
  for (int j = 0; j < 4; ++j) {
    if (i0 + j < n) {
      offs[i0 + j] = p;
      cursor[(size_t)(i0 + j) * 8] = p + 1;   // slot p reserved for self-loop
    }
    p += c[j];
  }
  if (b == gridDim.x - 1 && t == 255)
    offs[n] = bscan[b] + wtot[0] + wtot[1] + wtot[2] + wtot[3];
}

// fill CSR (sorted by destination): edges[pos] = {src row, norm}
// self-loop goes atomic-free to slot offs[i]; dynamic edges via padded cursor atomics
__global__ void fill_kernel(const int* __restrict__ ei, const float* __restrict__ ew,
                            const float* __restrict__ dinv, const int* __restrict__ offs,
                            int* __restrict__ cursor, int2* __restrict__ edges,
                            int nE, int nN) {
  int i = blockIdx.x * blockDim.x + threadIdx.x;
  if (i < nN) {                       // self-loop of node i
    float di = dinv[i];
    edges[offs[i]] = make_int2(i, __float_as_int(di * di));
  } else if (i < nN + nE) {
    int e = i - nN;
    int r = ei[e], c = ei[nE + e];
    float w = dinv[r] * ew[e] * dinv[c];
    int pos = atomicAdd(&cursor[(size_t)c * 8], 1);
    edges[pos] = make_int2(r, __float_as_int(w));
  }
}

// ---------------- W split+transpose: W[K][N] f32 -> Wt hi/lo [N][K] bf16 ----------------

__global__ void wsplit_kernel(const float* __restrict__ W, unsigned short* __restrict__ Th,
                              unsigned short* __restrict__ Tl, int K, int N) {
  int id = blockIdx.x * blockDim.x + threadIdx.x;
  if (id >= K * N) return;
  int k = id % K, n = id / K;           // consecutive id -> consecutive k -> coalesced writes
  float f = W[(size_t)k * N + n];
  __bf16 hb = (__bf16)f;
  float hf = (float)hb;
  __bf16 lb = (__bf16)(f - hf);
  Th[id] = __builtin_bit_cast(unsigned short, hb);
  Tl[id] = __builtin_bit_cast(unsigned short, lb);
}

// ---------------- split-bf16 MFMA GEMM, big-tile 2-phase LDS pipeline ----------------
// Y[M,N] = X[M,K] @ W[K,N];  Y ~= Xh@Wh + Xl@Wh + Xh@Wl  (Xl@Wl dropped, ~2^-18)
// WR x WC waves (64 lanes each); wave tile = 32 rows (MF=2) x 64 cols; BM = WR*32.
// Per K-chunk (BK=32): A f32 tile + B=W^T hi/lo bf16 staged via global_load_lds (16B),
// double-buffered, one barrier per chunk. Bigger tile => more bytes+compute per stage
// (in-flight depth was the round-8 limiter).
// Swizzles (rule #21): LDS dest linear; global source pre-permuted, ds_read un-permutes.
//   A row=128B=8 granules:  content[p] = granule p ^ (row&7)   -> reads 2-way aliased
//   B col= 64B=4 granules:  content[p] = granule p ^ ((col>>2)&3) -> reads 2-way aliased
template <int K, int N, int WR, int WC>
__global__ void __launch_bounds__(WR * WC * 64, 4) gemm_mfma_kernel(
    const float* __restrict__ X, const unsigned short* __restrict__ Bth,
    const unsigned short* __restrict__ Btl, float* __restrict__ Y, int M) {
  constexpr int NW = WR * WC;
  constexpr int BM = WR * 32;
  constexpr int NI = K / 32;
  constexpr int ASLOTS = (BM / 8) / NW;   // 1KB A slots per wave
  constexpr int BSLOTS = (N / 8) / NW;    // 1KB B slots per wave (hi+lo combined)

  __shared__ float          As[2][BM * 32];
  __shared__ unsigned short Bs[2][2][N * 32];

  int tid = threadIdx.x;
  int lane = tid & 63, wid = tid >> 6;
  int wr = wid / WC, wc = wid % WC;
  int row0blk = blockIdx.x * BM;
  int row0 = row0blk + wr * 32;
  int rlo = lane & 15;
  int khi = lane >> 4;

  f32x4 acc[2][4] = {};

  auto stage = [&](int t, int buf) {
    int kb = t * 32;
    // A: slot = 8 rows x 32 floats; lane: row = slot*8 + (l>>3), src granule (l&7)^(l>>3)
#pragma unroll
    for (int i = 0; i < ASLOTS; ++i) {
      int slot = wid * ASLOTS + i;
      int rt = slot * 8 + (lane >> 3);
      int gr = row0blk + rt; gr = gr < M ? gr : M - 1;
      int gs = (lane & 7) ^ (lane >> 3);
      GLDS(X + (size_t)gr * K + kb + gs * 4, &As[buf][slot * 256]);
    }
    // B: slot = 16 cols x 32 shorts; lane: col = idx*16 + (l>>2), src granule (l&3)^(l>>4)
#pragma unroll
    for (int i = 0; i < BSLOTS; ++i) {
      int slot = wid * BSLOTS + i;
      int half = slot / (N / 16);
      int idx = slot % (N / 16);
      const unsigned short* Wt = half ? Btl : Bth;
      int c = idx * 16 + (lane >> 2);
      int gs = (lane & 3) ^ (lane >> 4);
      GLDS(Wt + (size_t)c * K + kb + gs * 8, &Bs[buf][half][idx * 512]);
    }
  };

  stage(0, 0);
  __syncthreads();

#pragma unroll 1
  for (int t = 0; t < NI; ++t) {
    int buf = t & 1;
    if (t + 1 < NI) stage(t + 1, buf ^ 1);

    // A fragments (un-swizzle granule ^ (row&7)), f32 -> bf16 hi/lo
    bf16x8 ah[2], al[2];
#pragma unroll
    for (int m = 0; m < 2; ++m) {
      int rt = wr * 32 + m * 16 + rlo;
      int p0 = (khi * 2) ^ (rlo & 7), p1 = (khi * 2 + 1) ^ (rlo & 7);
      f32x4 v0 = *reinterpret_cast<const f32x4*>(&As[buf][rt * 32 + p0 * 4]);
      f32x4 v1 = *reinterpret_cast<const f32x4*>(&As[buf][rt * 32 + p1 * 4]);
      float f[8] = {v0.x, v0.y, v0.z, v0.w, v1.x, v1.y, v1.z, v1.w};
#pragma unroll
      for (int i = 0; i < 8; ++i) {
        __bf16 hv = (__bf16)f[i];
        ah[m][i] = hv;
        al[m][i] = (__bf16)(f[i] - (float)hv);
      }
    }
    // B fragments (un-swizzle granule ^ ((col>>2)&3))
    short8 bh[4], bl[4];
#pragma unroll
    for (int n = 0; n < 4; ++n) {
      int c = wc * 64 + n * 16 + rlo;
      int pos = khi ^ (rlo >> 2);
      bh[n] = *reinterpret_cast<const short8*>(&Bs[buf][0][c * 32 + pos * 8]);
      bl[n] = *reinterpret_cast<const short8*>(&Bs[buf][1][c * 32 + pos * 8]);
    }
#pragma unroll
    for (int m = 0; m < 2; ++m)
#pragma unroll
      for (int n = 0; n < 4; ++n)
        acc[m][n] = __builtin_amdgcn_mfma_f32_16x16x32_bf16(
            ah[m], __builtin_bit_cast(bf16x8, bh[n]), acc[m][n], 0, 0, 0);
#pragma unroll
    for (int m = 0; m < 2; ++m)
#pragma unroll
      for (int n = 0; n < 4; ++n)
        acc[m][n] = __builtin_amdgcn_mfma_f32_16x16x32_bf16(
            al[m], __builtin_bit_cast(bf16x8, bh[n]), acc[m][n], 0, 0, 0);
#pragma unroll
    for (int m = 0; m < 2; ++m)
#pragma unroll
      for (int n = 0; n < 4; ++n)
        acc[m][n] = __builtin_amdgcn_mfma_f32_16x16x32_bf16(
            ah[m], __builtin_bit_cast(bf16x8, bl[n]), acc[m][n], 0, 0, 0);
    __syncthreads();
  }

  // C/D layout: col = lane&15, row = (lane>>4)*4 + reg  [m89-verified]
#pragma unroll
  for (int m = 0; m < 2; ++m)
#pragma unroll
    for (int j = 0; j < 4; ++j) {
      int row = row0 + m * 16 + khi * 4 + j;
      if (row < M) {
#pragma unroll
        for (int n = 0; n < 4; ++n)
          Y[(size_t)row * N + wc * 64 + n * 16 + rlo] = acc[m][n][j];
      }
    }
}

// ---------------- CSR aggregation: out[n] = bias + sum_e w*feat[row] over edge records ----
// F/4 lanes per node (float4 loads), 4-deep edge unroll; edge = {row, norm} in one int2
template <int F, bool RELU>
__global__ void __launch_bounds__(256) agg_kernel(const float* __restrict__ feat,
                                                  const int* __restrict__ offs,
                                                  const int2* __restrict__ edges,
                                                  const float* __restrict__ bias,
                                                  float* __restrict__ out, int n) {
  constexpr int LPN = F / 4;        // lanes per node (32 for F=128, 16 for F=64)
  constexpr int NPW = 64 / LPN;     // nodes per wave (2 / 4)
  constexpr int NPB = 4 * NPW;      // nodes per 256-thread block
  int wid = threadIdx.x >> 6;
  int lane = threadIdx.x & 63;
  int node = blockIdx.x * NPB + wid * NPW + lane / LPN;
  int lf = (lane % LPN) * 4;        // feature offset
  if (node >= n) return;
  int e0 = offs[node], e1 = offs[node + 1];

  float4 acc = *reinterpret_cast<const float4*>(&bias[lf]);
  int e = e0;
  for (; e + 4 <= e1; e += 4) {
    int2 q0 = edges[e], q1 = edges[e + 1], q2 = edges[e + 2], q3 = edges[e + 3];
    float w0 = __int_as_float(q0.y), w1 = __int_as_float(q1.y);
    float w2 = __int_as_float(q2.y), w3 = __int_as_float(q3.y);
    float4 f0 = *reinterpret_cast<const float4*>(&feat[(size_t)q0.x * F + lf]);
    float4 f1 = *reinterpret_cast<const float4*>(&feat[(size_t)q1.x * F + lf]);
    float4 f2 = *reinterpret_cast<const float4*>(&feat[(size_t)q2.x * F + lf]);
    float4 f3 = *reinterpret_cast<const float4*>(&feat[(size_t)q3.x * F + lf]);
    acc.x = fmaf(w0, f0.x, acc.x); acc.y = fmaf(w0, f0.y, acc.y);
    acc.z = fmaf(w0, f0.z, acc.z); acc.w = fmaf(w0, f0.w, acc.w);
    acc.x = fmaf(w1, f1.x, acc.x); acc.y = fmaf(w1, f1.y, acc.y);
    acc.z = fmaf(w1, f1.z, acc.z); acc.w = fmaf(w1, f1.w, acc.w);
    acc.x = fmaf(w2, f2.x, acc.x); acc.y = fmaf(w2, f2.y, acc.y);
    acc.z = fmaf(w2, f2.z, acc.z); acc.w = fmaf(w2, f2.w, acc.w);
    acc.x = fmaf(w3, f3.x, acc.x); acc.y = fmaf(w3, f3.y, acc.y);
    acc.z = fmaf(w3, f3.z, acc.z); acc.w = fmaf(w3, f3.w, acc.w);
  }
  for (; e < e1; ++e) {
    int2 q = edges[e];
    float w = __int_as_float(q.y);
    float4 f = *reinterpret_cast<const float4*>(&feat[(size_t)q.x * F + lf]);
    acc.x = fmaf(w, f.x, acc.x); acc.y = fmaf(w, f.y, acc.y);
    acc.z = fmaf(w, f.z, acc.z); acc.w = fmaf(w, f.w, acc.w);
  }
  if (RELU) {
    acc.x = fmaxf(acc.x, 0.f); acc.y = fmaxf(acc.y, 0.f);
    acc.z = fmaxf(acc.z, 0.f); acc.w = fmaxf(acc.w, 0.f);
  }
  *reinterpret_cast<float4*>(&out[(size_t)node * F + lf]) = acc;
}

// ---------------- launch ----------------

extern "C" void kernel_launch(void* const* d_in, const int* in_sizes, int n_in,
                              void* d_out, int out_size, void* d_ws, size_t ws_size,
                              hipStream_t stream) {
  const float* x  = (const float*)d_in[0];
  const int*   ei = (const int*)d_in[1];     // [2, E] int
  const float* ew = (const float*)d_in[2];
  const float* W1 = (const float*)d_in[3];
  const float* b1 = (const float*)d_in[4];
  const float* W2 = (const float*)d_in[5];
  const float* b2 = (const float*)d_in[6];
  float* out = (float*)d_out;

  const int N = NNODES, E = NEDGES, EP = NNODES + NEDGES;
  const int NB = (N + 1023) / 1024;          // scan blocks (49)

  char* p = (char*)d_ws;
  auto alloc = [&](size_t bytes) { char* r = p; p += (bytes + 255) & ~(size_t)255; return r; };
  unsigned long long* packed = (unsigned long long*)alloc((size_t)N * 32); // 1/32B sector
  float* dinv   = (float*)alloc((size_t)N * 4);
  int*   counts = (int*)  alloc((size_t)N * 4);
  int*   offs   = (int*)  alloc((size_t)(N + 1) * 4);
  int*   cursor = (int*)  alloc((size_t)N * 32);       // 1 counter per 32B sector
  int*   bsum   = (int*)  alloc((size_t)64 * 4);
  int2*  edges  = (int2*) alloc((size_t)EP * 8);       // {row, norm}
  float* xw     = (float*)alloc((size_t)N * HID_C * 4); // layer1 pre-agg; reused as h2
  float* h      = (float*)alloc((size_t)N * HID_C * 4); // layer1 output
  unsigned short* W1th = (unsigned short*)alloc((size_t)IN_C * HID_C * 2);
  unsigned short* W1tl = (unsigned short*)alloc((size_t)IN_C * HID_C * 2);
  unsigned short* W2th = (unsigned short*)alloc((size_t)HID_C * OUT_C * 2);
  unsigned short* W2tl = (unsigned short*)alloc((size_t)HID_C * OUT_C * 2);

  hipMemsetAsync(packed, 0, (size_t)N * 32, stream);
  deg_count_kernel<<<(E + 255) / 256, 256, 0, stream>>>(ei, ew, packed, E);
  decode_kernel<<<(N + 255) / 256, 256, 0, stream>>>(packed, dinv, counts, N);
  scan_partial_kernel<<<NB, 256, 0, stream>>>(counts, bsum, N);
  scan_bsum_kernel<<<1, 64, 0, stream>>>(bsum, NB);
  scan_final_kernel<<<NB, 256, 0, stream>>>(counts, bsum, offs, cursor, N);
  fill_kernel<<<(EP + 255) / 256, 256, 0, stream>>>(ei, ew, dinv, offs, cursor, edges, E, N);
  wsplit_kernel<<<(IN_C * HID_C + 255) / 256, 256, 0, stream>>>(W1, W1th, W1tl, IN_C, HID_C);
  wsplit_kernel<<<(HID_C * OUT_C + 255) / 256, 256, 0, stream>>>(W2, W2th, W2tl, HID_C, OUT_C);

  // layer 1: xw = x @ W1 ; h = relu(agg(xw) + b1)   [BM=128, N=128, 8 waves]
  gemm_mfma_kernel<IN_C, HID_C, 4, 2><<<(N + 127) / 128, 512, 0, stream>>>(x, W1th, W1tl, xw, N);
  agg_kernel<HID_C, true><<<(N + 7) / 8, 256, 0, stream>>>(xw, offs, edges, b1, h, N);

  // layer 2: h2 = h @ W2 ; out = agg(h2) + b2       [BM=256, N=64, 8 waves]
  gemm_mfma_kernel<HID_C, OUT_C, 8, 1><<<(N + 255) / 256, 512, 0, stream>>>(h, W2th, W2tl, xw, N);
  agg_kernel<OUT_C, false><<<(N + 15) / 16, 256, 0, stream>>>(xw, offs, edges, b2, out, N);
}

// Round 10
// 191.089 us; speedup vs baseline: 2.3271x; 1.1789x over previous
//
#include <hip/hip_runtime.h>

#define NNODES 50000
#define NEDGES 800000
#define IN_C   512
#define HID_C  128
#define OUT_C  64

typedef float  f32x4  __attribute__((ext_vector_type(4)));
typedef __bf16 bf16x8 __attribute__((ext_vector_type(8)));
typedef short  short8 __attribute__((ext_vector_type(8)));

#define GLDS(src, dst) \
  __builtin_amdgcn_global_load_lds( \
      (const __attribute__((address_space(1))) unsigned int*)(src), \
      (__attribute__((address_space(3))) unsigned int*)(dst), 16, 0, 0)

__device__ __forceinline__ float bf2f(unsigned short u) {
  unsigned int x = (unsigned int)u << 16;
  return __builtin_bit_cast(float, x);
}

// ---------------- graph prep ----------------
// deg+count packed in ONE u64 per node: bits[0:20)=count, bits[20:64)=deg in 2^-24 units.
// One node per 32B sector (stride 4 u64) to spread atomic contention.

__global__ void deg_count_kernel(const int* __restrict__ ei, const float* __restrict__ ew,
                                 unsigned long long* __restrict__ packed, int nE) {
  int e = blockIdx.x * blockDim.x + threadIdx.x;
  if (e < nE) {
    int c = ei[nE + e];               // edge_index[1][e] (destination)
    unsigned int fx = __float2uint_rn(ew[e] * 16777216.0f);   // ew in [0,1)
    atomicAdd(&packed[(size_t)c * 4], ((unsigned long long)fx << 20) | 1ULL);
  }
}

// decode packed -> dinv (rsqrt) + dense counts (for scan)
__global__ void decode_kernel(const unsigned long long* __restrict__ packed,
                              float* __restrict__ dinv, int* __restrict__ counts, int n) {
  int i = blockIdx.x * blockDim.x + threadIdx.x;
  if (i < n) {
    unsigned long long p = packed[(size_t)i * 4];
    counts[i] = (int)(p & 0xFFFFFULL) + 1;                     // + self-loop slot
    float deg = (float)((double)(p >> 20) * (1.0 / 16777216.0) + 1.0);  // + self-loop w=1
    dinv[i] = rsqrtf(deg);                                     // deg >= 1 always
  }
}

// ---- parallel exclusive scan over counts[n] -> offs[0..n] (+cursor=offs+1, 32B-strided) ----

__global__ void __launch_bounds__(256) scan_partial_kernel(const int* __restrict__ counts,
                                                           int* __restrict__ bsum, int n) {
  int t = threadIdx.x;
  int i0 = blockIdx.x * 1024 + t * 4;
  int s = 0;
  if (i0 + 3 < n) {
    int4 v = *reinterpret_cast<const int4*>(&counts[i0]);
    s = v.x + v.y + v.z + v.w;
  } else {
#pragma unroll
    for (int j = 0; j < 4; ++j) if (i0 + j < n) s += counts[i0 + j];
  }
#pragma unroll
  for (int off = 32; off; off >>= 1) s += __shfl_down(s, off);
  __shared__ int ws[4];
  if ((t & 63) == 0) ws[t >> 6] = s;
  __syncthreads();
  if (t == 0) bsum[blockIdx.x] = ws[0] + ws[1] + ws[2] + ws[3];
}

__global__ void scan_bsum_kernel(int* __restrict__ bsum, int nb) {  // 1 block, 64 thr; nb<=64
  int lane = threadIdx.x;
  int orig = lane < nb ? bsum[lane] : 0;
  int v = orig;
#pragma unroll
  for (int off = 1; off < 64; off <<= 1) {
    int u = __shfl_up(v, off);
    if (lane >= off) v += u;
  }
  if (lane < nb) bsum[lane] = v - orig;   // exclusive
}

__global__ void __launch_bounds__(256) scan_final_kernel(const int* __restrict__ counts,
                                                         const int* __restrict__ bscan,
                                                         int* __restrict__ offs,
                                                         int* __restrict__ cursor, int n) {
  int t = threadIdx.x;
  int lane = t & 63, wid = t >> 6;
  int b = blockIdx.x;
  int i0 = b * 1024 + t * 4;
  int c[4];
#pragma unroll
  for (int j = 0; j < 4; ++j) c[j] = (i0 + j < n) ? counts[i0 + j] : 0;
  int s = c[0] + c[1] + c[2] + c[3];
  int v = s;
#pragma unroll
  for (int off = 1; off < 64; off <<= 1) {
    int u = __shfl_up(v, off);
    if (lane >= off) v += u;
  }
  __shared__ int wtot[4];
  if (lane == 63) wtot[wid] = v;
  __syncthreads();
  int wpre = 0;
#pragma unroll
  for (int w = 0; w < 4; ++w) if (w < wid) wpre += wtot[w];
  int p = bscan[b] + wpre + (v - s);     // exclusive prefix for this thread's first elem
#pragma unroll
  for (int j = 0; j < 4; ++j) {
    if (i0 + j < n) {
      offs[i0 + j] = p;
      cursor[(size_t)(i0 + j) * 8] = p + 1;   // slot p reserved for self-loop
    }
    p += c[j];
  }
  if (b == gridDim.x - 1 && t == 255)
    offs[n] = bscan[b] + wtot[0] + wtot[1] + wtot[2] + wtot[3];
}

// fill CSR (sorted by destination): edges[pos] = {src row, norm}
// self-loop goes atomic-free to slot offs[i]; dynamic edges via padded cursor atomics
__global__ void fill_kernel(const int* __restrict__ ei, const float* __restrict__ ew,
                            const float* __restrict__ dinv, const int* __restrict__ offs,
                            int* __restrict__ cursor, int2* __restrict__ edges,
                            int nE, int nN) {
  int i = blockIdx.x * blockDim.x + threadIdx.x;
  if (i < nN) {                       // self-loop of node i
    float di = dinv[i];
    edges[offs[i]] = make_int2(i, __float_as_int(di * di));
  } else if (i < nN + nE) {
    int e = i - nN;
    int r = ei[e], c = ei[nE + e];
    float w = dinv[r] * ew[e] * dinv[c];
    int pos = atomicAdd(&cursor[(size_t)c * 8], 1);
    edges[pos] = make_int2(r, __float_as_int(w));
  }
}

// ---------------- W split+transpose: W[K][N] f32 -> Wt hi/lo [N][K] bf16 ----------------

__global__ void wsplit_kernel(const float* __restrict__ W, unsigned short* __restrict__ Th,
                              unsigned short* __restrict__ Tl, int K, int N) {
  int id = blockIdx.x * blockDim.x + threadIdx.x;
  if (id >= K * N) return;
  int k = id % K, n = id / K;           // consecutive id -> consecutive k -> coalesced writes
  float f = W[(size_t)k * N + n];
  __bf16 hb = (__bf16)f;
  float hf = (float)hb;
  __bf16 lb = (__bf16)(f - hf);
  Th[id] = __builtin_bit_cast(unsigned short, hb);
  Tl[id] = __builtin_bit_cast(unsigned short, lb);
}

// ---------------- split-bf16 MFMA GEMM, big-tile 2-phase LDS pipeline ----------------
// Y[M,N] = X[M,K] @ W[K,N] -> bf16 (RNE);  Y ~= Xh@Wh + Xl@Wh + Xh@Wl  (Xl@Wl dropped)
// WR x WC waves; wave tile = 32 rows x 64 cols; BM = WR*32.
// Per K-chunk (BK=32): A f32 tile + B=W^T hi/lo bf16 staged via global_load_lds (16B),
// double-buffered, one barrier per chunk.
// Swizzles (rule #21): LDS dest linear; global source pre-permuted, ds_read un-permutes.
//   A row=128B=8 granules:  content[p] = granule p ^ (row&7)   -> reads 2-way aliased
//   B col= 64B=4 granules:  content[p] = granule p ^ ((col>>2)&3) -> reads 2-way aliased
template <int K, int N, int WR, int WC>
__global__ void __launch_bounds__(WR * WC * 64, 4) gemm_mfma_kernel(
    const float* __restrict__ X, const unsigned short* __restrict__ Bth,
    const unsigned short* __restrict__ Btl, unsigned short* __restrict__ Y, int M) {
  constexpr int NW = WR * WC;
  constexpr int BM = WR * 32;
  constexpr int NI = K / 32;
  constexpr int ASLOTS = (BM / 8) / NW;   // 1KB A slots per wave
  constexpr int BSLOTS = (N / 8) / NW;    // 1KB B slots per wave (hi+lo combined)

  __shared__ float          As[2][BM * 32];
  __shared__ unsigned short Bs[2][2][N * 32];

  int tid = threadIdx.x;
  int lane = tid & 63, wid = tid >> 6;
  int wr = wid / WC, wc = wid % WC;
  int row0blk = blockIdx.x * BM;
  int row0 = row0blk + wr * 32;
  int rlo = lane & 15;
  int khi = lane >> 4;

  f32x4 acc[2][4] = {};

  auto stage = [&](int t, int buf) {
    int kb = t * 32;
#pragma unroll
    for (int i = 0; i < ASLOTS; ++i) {
      int slot = wid * ASLOTS + i;
      int rt = slot * 8 + (lane >> 3);
      int gr = row0blk + rt; gr = gr < M ? gr : M - 1;
      int gs = (lane & 7) ^ (lane >> 3);
      GLDS(X + (size_t)gr * K + kb + gs * 4, &As[buf][slot * 256]);
    }
#pragma unroll
    for (int i = 0; i < BSLOTS; ++i) {
      int slot = wid * BSLOTS + i;
      int half = slot / (N / 16);
      int idx = slot % (N / 16);
      const unsigned short* Wt = half ? Btl : Bth;
      int c = idx * 16 + (lane >> 2);
      int gs = (lane & 3) ^ (lane >> 4);
      GLDS(Wt + (size_t)c * K + kb + gs * 8, &Bs[buf][half][idx * 512]);
    }
  };

  stage(0, 0);
  __syncthreads();

#pragma unroll 1
  for (int t = 0; t < NI; ++t) {
    int buf = t & 1;
    if (t + 1 < NI) stage(t + 1, buf ^ 1);

    // A fragments (un-swizzle granule ^ (row&7)), f32 -> bf16 hi/lo
    bf16x8 ah[2], al[2];
#pragma unroll
    for (int m = 0; m < 2; ++m) {
      int rt = wr * 32 + m * 16 + rlo;
      int p0 = (khi * 2) ^ (rlo & 7), p1 = (khi * 2 + 1) ^ (rlo & 7);
      f32x4 v0 = *reinterpret_cast<const f32x4*>(&As[buf][rt * 32 + p0 * 4]);
      f32x4 v1 = *reinterpret_cast<const f32x4*>(&As[buf][rt * 32 + p1 * 4]);
      float f[8] = {v0.x, v0.y, v0.z, v0.w, v1.x, v1.y, v1.z, v1.w};
#pragma unroll
      for (int i = 0; i < 8; ++i) {
        __bf16 hv = (__bf16)f[i];
        ah[m][i] = hv;
        al[m][i] = (__bf16)(f[i] - (float)hv);
      }
    }
    // B fragments (un-swizzle granule ^ ((col>>2)&3))
    short8 bh[4], bl[4];
#pragma unroll
    for (int n = 0; n < 4; ++n) {
      int c = wc * 64 + n * 16 + rlo;
      int pos = khi ^ (rlo >> 2);
      bh[n] = *reinterpret_cast<const short8*>(&Bs[buf][0][c * 32 + pos * 8]);
      bl[n] = *reinterpret_cast<const short8*>(&Bs[buf][1][c * 32 + pos * 8]);
    }
#pragma unroll
    for (int m = 0; m < 2; ++m)
#pragma unroll
      for (int n = 0; n < 4; ++n)
        acc[m][n] = __builtin_amdgcn_mfma_f32_16x16x32_bf16(
            ah[m], __builtin_bit_cast(bf16x8, bh[n]), acc[m][n], 0, 0, 0);
#pragma unroll
    for (int m = 0; m < 2; ++m)
#pragma unroll
      for (int n = 0; n < 4; ++n)
        acc[m][n] = __builtin_amdgcn_mfma_f32_16x16x32_bf16(
            al[m], __builtin_bit_cast(bf16x8, bh[n]), acc[m][n], 0, 0, 0);
#pragma unroll
    for (int m = 0; m < 2; ++m)
#pragma unroll
      for (int n = 0; n < 4; ++n)
        acc[m][n] = __builtin_amdgcn_mfma_f32_16x16x32_bf16(
            ah[m], __builtin_bit_cast(bf16x8, bl[n]), acc[m][n], 0, 0, 0);
    __syncthreads();
  }

  // C/D layout: col = lane&15, row = (lane>>4)*4 + reg; store bf16 (RNE)
#pragma unroll
  for (int m = 0; m < 2; ++m)
#pragma unroll
    for (int j = 0; j < 4; ++j) {
      int row = row0 + m * 16 + khi * 4 + j;
      if (row < M) {
#pragma unroll
        for (int n = 0; n < 4; ++n) {
          __bf16 q = (__bf16)acc[m][n][j];
          Y[(size_t)row * N + wc * 64 + n * 16 + rlo] = __builtin_bit_cast(unsigned short, q);
        }
      }
    }
}

// ---------------- CSR aggregation over bf16 features ----------------
// out[n] (f32) = bias + sum_e w*feat_bf16[row];  F/8 lanes per node (short8 = 8 bf16/lane),
// 4-deep edge unroll; edge = {row, norm} in one int2 (broadcast within node's lane group)
template <int F, bool RELU>
__global__ void __launch_bounds__(256) agg_kernel(const unsigned short* __restrict__ feat,
                                                  const int* __restrict__ offs,
                                                  const int2* __restrict__ edges,
                                                  const float* __restrict__ bias,
                                                  float* __restrict__ out, int n) {
  constexpr int LPN = F / 8;        // lanes per node (16 for F=128, 8 for F=64)
  constexpr int NPW = 64 / LPN;     // nodes per wave (4 / 8)
  constexpr int NPB = 4 * NPW;      // nodes per 256-thread block
  int wid = threadIdx.x >> 6;
  int lane = threadIdx.x & 63;
  int node = blockIdx.x * NPB + wid * NPW + lane / LPN;
  int lf = (lane % LPN) * 8;        // feature offset (8 bf16 per lane)
  if (node >= n) return;
  int e0 = offs[node], e1 = offs[node + 1];

  float acc[8];
#pragma unroll
  for (int j = 0; j < 8; ++j) acc[j] = bias[lf + j];

  auto fmaEdge = [&](int2 q) {
    float w = __int_as_float(q.y);
    short8 v = *reinterpret_cast<const short8*>(&feat[(size_t)q.x * F + lf]);
#pragma unroll
    for (int j = 0; j < 8; ++j)
      acc[j] = fmaf(w, bf2f((unsigned short)v[j]), acc[j]);
  };

  int e = e0;
  for (; e + 4 <= e1; e += 4) {
    int2 q0 = edges[e], q1 = edges[e + 1], q2 = edges[e + 2], q3 = edges[e + 3];
    fmaEdge(q0); fmaEdge(q1); fmaEdge(q2); fmaEdge(q3);
  }
  for (; e < e1; ++e) fmaEdge(edges[e]);

  if (RELU) {
#pragma unroll
    for (int j = 0; j < 8; ++j) acc[j] = fmaxf(acc[j], 0.f);
  }
  float4 o0 = make_float4(acc[0], acc[1], acc[2], acc[3]);
  float4 o1 = make_float4(acc[4], acc[5], acc[6], acc[7]);
  *reinterpret_cast<float4*>(&out[(size_t)node * F + lf]) = o0;
  *reinterpret_cast<float4*>(&out[(size_t)node * F + lf + 4]) = o1;
}

// ---------------- launch ----------------

extern "C" void kernel_launch(void* const* d_in, const int* in_sizes, int n_in,
                              void* d_out, int out_size, void* d_ws, size_t ws_size,
                              hipStream_t stream) {
  const float* x  = (const float*)d_in[0];
  const int*   ei = (const int*)d_in[1];     // [2, E] int
  const float* ew = (const float*)d_in[2];
  const float* W1 = (const float*)d_in[3];
  const float* b1 = (const float*)d_in[4];
  const float* W2 = (const float*)d_in[5];
  const float* b2 = (const float*)d_in[6];
  float* out = (float*)d_out;

  const int N = NNODES, E = NEDGES, EP = NNODES + NEDGES;
  const int NB = (N + 1023) / 1024;          // scan blocks (49)

  char* p = (char*)d_ws;
  auto alloc = [&](size_t bytes) { char* r = p; p += (bytes + 255) & ~(size_t)255; return r; };
  unsigned long long* packed = (unsigned long long*)alloc((size_t)N * 32); // 1/32B sector
  float* dinv   = (float*)alloc((size_t)N * 4);
  int*   counts = (int*)  alloc((size_t)N * 4);
  int*   offs   = (int*)  alloc((size_t)(N + 1) * 4);
  int*   cursor = (int*)  alloc((size_t)N * 32);       // 1 counter per 32B sector
  int*   bsum   = (int*)  alloc((size_t)64 * 4);
  int2*  edges  = (int2*) alloc((size_t)EP * 8);       // {row, norm}
  unsigned short* xw = (unsigned short*)alloc((size_t)N * HID_C * 2); // bf16 pre-agg (reused as h2)
  float* h      = (float*)alloc((size_t)N * HID_C * 4); // layer1 output (f32)
  unsigned short* W1th = (unsigned short*)alloc((size_t)IN_C * HID_C * 2);
  unsigned short* W1tl = (unsigned short*)alloc((size_t)IN_C * HID_C * 2);
  unsigned short* W2th = (unsigned short*)alloc((size_t)HID_C * OUT_C * 2);
  unsigned short* W2tl = (unsigned short*)alloc((size_t)HID_C * OUT_C * 2);

  hipMemsetAsync(packed, 0, (size_t)N * 32, stream);
  deg_count_kernel<<<(E + 255) / 256, 256, 0, stream>>>(ei, ew, packed, E);
  decode_kernel<<<(N + 255) / 256, 256, 0, stream>>>(packed, dinv, counts, N);
  scan_partial_kernel<<<NB, 256, 0, stream>>>(counts, bsum, N);
  scan_bsum_kernel<<<1, 64, 0, stream>>>(bsum, NB);
  scan_final_kernel<<<NB, 256, 0, stream>>>(counts, bsum, offs, cursor, N);
  fill_kernel<<<(EP + 255) / 256, 256, 0, stream>>>(ei, ew, dinv, offs, cursor, edges, E, N);
  wsplit_kernel<<<(IN_C * HID_C + 255) / 256, 256, 0, stream>>>(W1, W1th, W1tl, IN_C, HID_C);
  wsplit_kernel<<<(HID_C * OUT_C + 255) / 256, 256, 0, stream>>>(W2, W2th, W2tl, HID_C, OUT_C);

  // layer 1: xw = bf16(x @ W1) ; h = relu(agg(xw) + b1)   [BM=128, N=128, 8 waves]
  gemm_mfma_kernel<IN_C, HID_C, 4, 2><<<(N + 127) / 128, 512, 0, stream>>>(x, W1th, W1tl, xw, N);
  agg_kernel<HID_C, true><<<(N + 15) / 16, 256, 0, stream>>>(xw, offs, edges, b1, h, N);

  // layer 2: h2 = bf16(h @ W2) ; out = agg(h2) + b2       [BM=256, N=64, 8 waves]
  gemm_mfma_kernel<HID_C, OUT_C, 8, 1><<<(N + 255) / 256, 512, 0, stream>>>(h, W2th, W2tl, xw, N);
  agg_kernel<OUT_C, false><<<(N + 31) / 32, 256, 0, stream>>>(xw, offs, edges, b2, out, N);
}

// Round 11
// 162.568 us; speedup vs baseline: 2.7354x; 1.1754x over previous
//
#include <hip/hip_runtime.h>

#define NNODES 50000
#define NEDGES 800000
#define IN_C   512
#define HID_C  128
#define OUT_C  64

typedef float  f32x4  __attribute__((ext_vector_type(4)));
typedef __bf16 bf16x8 __attribute__((ext_vector_type(8)));
typedef short  short8 __attribute__((ext_vector_type(8)));

#define GLDS(src, dst) \
  __builtin_amdgcn_global_load_lds( \
      (const __attribute__((address_space(1))) unsigned int*)(src), \
      (__attribute__((address_space(3))) unsigned int*)(dst), 16, 0, 0)

__device__ __forceinline__ float bf2f(unsigned short u) {
  unsigned int x = (unsigned int)u << 16;
  return __builtin_bit_cast(float, x);
}

// ---------------- graph prep ----------------
// deg+count packed in ONE u64 per node: bits[0:20)=count, bits[20:64)=deg in 2^-24 units.
// One node per 32B sector (stride 4 u64) to spread atomic contention.
// The returning atomicAdd's old count field == this edge's rank within its destination,
// which makes the CSR fill pass atomic-free.

__global__ void clear_kernel(int4* __restrict__ p, int n4) {
  int i = blockIdx.x * blockDim.x + threadIdx.x;
  if (i < n4) p[i] = make_int4(0, 0, 0, 0);
}

__global__ void deg_count_kernel(const int* __restrict__ ei, const float* __restrict__ ew,
                                 unsigned long long* __restrict__ packed,
                                 unsigned short* __restrict__ rank, int nE) {
  int e = blockIdx.x * blockDim.x + threadIdx.x;
  if (e < nE) {
    int c = ei[nE + e];               // edge_index[1][e] (destination)
    unsigned int fx = __float2uint_rn(ew[e] * 16777216.0f);   // ew in [0,1)
    unsigned long long old =
        atomicAdd(&packed[(size_t)c * 4], ((unsigned long long)fx << 20) | 1ULL);
    rank[e] = (unsigned short)(old & 0xFFFFFULL);   // edges-before-me at this dest
  }
}

// decode packed -> dinv (rsqrt) + dense counts (for scan)
__global__ void decode_kernel(const unsigned long long* __restrict__ packed,
                              float* __restrict__ dinv, int* __restrict__ counts, int n) {
  int i = blockIdx.x * blockDim.x + threadIdx.x;
  if (i < n) {
    unsigned long long p = packed[(size_t)i * 4];
    counts[i] = (int)(p & 0xFFFFFULL) + 1;                     // + self-loop slot
    float deg = (float)((double)(p >> 20) * (1.0 / 16777216.0) + 1.0);  // + self-loop w=1
    dinv[i] = rsqrtf(deg);                                     // deg >= 1 always
  }
}

// ---- parallel exclusive scan over counts[n] -> offs[0..n] ----

__global__ void __launch_bounds__(256) scan_partial_kernel(const int* __restrict__ counts,
                                                           int* __restrict__ bsum, int n) {
  int t = threadIdx.x;
  int i0 = blockIdx.x * 1024 + t * 4;
  int s = 0;
  if (i0 + 3 < n) {
    int4 v = *reinterpret_cast<const int4*>(&counts[i0]);
    s = v.x + v.y + v.z + v.w;
  } else {
#pragma unroll
    for (int j = 0; j < 4; ++j) if (i0 + j < n) s += counts[i0 + j];
  }
#pragma unroll
  for (int off = 32; off; off >>= 1) s += __shfl_down(s, off);
  __shared__ int ws[4];
  if ((t & 63) == 0) ws[t >> 6] = s;
  __syncthreads();
  if (t == 0) bsum[blockIdx.x] = ws[0] + ws[1] + ws[2] + ws[3];
}

__global__ void scan_bsum_kernel(int* __restrict__ bsum, int nb) {  // 1 block, 64 thr; nb<=64
  int lane = threadIdx.x;
  int orig = lane < nb ? bsum[lane] : 0;
  int v = orig;
#pragma unroll
  for (int off = 1; off < 64; off <<= 1) {
    int u = __shfl_up(v, off);
    if (lane >= off) v += u;
  }
  if (lane < nb) bsum[lane] = v - orig;   // exclusive
}

__global__ void __launch_bounds__(256) scan_final_kernel(const int* __restrict__ counts,
                                                         const int* __restrict__ bscan,
                                                         int* __restrict__ offs, int n) {
  int t = threadIdx.x;
  int lane = t & 63, wid = t >> 6;
  int b = blockIdx.x;
  int i0 = b * 1024 + t * 4;
  int c[4];
#pragma unroll
  for (int j = 0; j < 4; ++j) c[j] = (i0 + j < n) ? counts[i0 + j] : 0;
  int s = c[0] + c[1] + c[2] + c[3];
  int v = s;
#pragma unroll
  for (int off = 1; off < 64; off <<= 1) {
    int u = __shfl_up(v, off);
    if (lane >= off) v += u;
  }
  __shared__ int wtot[4];
  if (lane == 63) wtot[wid] = v;
  __syncthreads();
  int wpre = 0;
#pragma unroll
  for (int w = 0; w < 4; ++w) if (w < wid) wpre += wtot[w];
  int p = bscan[b] + wpre + (v - s);     // exclusive prefix for this thread's first elem
#pragma unroll
  for (int j = 0; j < 4; ++j) {
    if (i0 + j < n) offs[i0 + j] = p;
    p += c[j];
  }
  if (b == gridDim.x - 1 && t == 255)
    offs[n] = bscan[b] + wtot[0] + wtot[1] + wtot[2] + wtot[3];
}

// fill CSR (sorted by destination), ATOMIC-FREE: pos = offs[c] + 1 + rank[e].
// edge record packed in u32: (row:16 | f16(norm):16). Self-loop at slot offs[i].
__global__ void fill_kernel(const int* __restrict__ ei, const float* __restrict__ ew,
                            const float* __restrict__ dinv, const int* __restrict__ offs,
                            const unsigned short* __restrict__ rank,
                            unsigned int* __restrict__ edges, int nE, int nN) {
  int i = blockIdx.x * blockDim.x + threadIdx.x;
  if (i < nN) {                       // self-loop of node i (coalesced: offs monotone)
    float di = dinv[i];
    _Float16 hf = (_Float16)(di * di);
    edges[offs[i]] = (unsigned int)i |
                     ((unsigned int)__builtin_bit_cast(unsigned short, hf) << 16);
  } else if (i < nN + nE) {
    int e = i - nN;
    int r = ei[e], c = ei[nE + e];
    float w = dinv[r] * ew[e] * dinv[c];
    _Float16 hf = (_Float16)w;
    int pos = offs[c] + 1 + (int)rank[e];
    edges[pos] = (unsigned int)r |
                 ((unsigned int)__builtin_bit_cast(unsigned short, hf) << 16);
  }
}

// ---------------- W split+transpose: W[K][N] f32 -> Wt hi/lo [N][K] bf16 ----------------

__global__ void wsplit_kernel(const float* __restrict__ W, unsigned short* __restrict__ Th,
                              unsigned short* __restrict__ Tl, int K, int N) {
  int id = blockIdx.x * blockDim.x + threadIdx.x;
  if (id >= K * N) return;
  int k = id % K, n = id / K;           // consecutive id -> consecutive k -> coalesced writes
  float f = W[(size_t)k * N + n];
  __bf16 hb = (__bf16)f;
  float hf = (float)hb;
  __bf16 lb = (__bf16)(f - hf);
  Th[id] = __builtin_bit_cast(unsigned short, hb);
  Tl[id] = __builtin_bit_cast(unsigned short, lb);
}

// ---------------- split-bf16 MFMA GEMM, big-tile 2-phase LDS pipeline ----------------
// Y[M,N] = X[M,K] @ W[K,N] -> bf16 (RNE);  Y ~= Xh@Wh + Xl@Wh + Xh@Wl  (Xl@Wl dropped)
// WR x WC waves; wave tile = 32 rows x 64 cols; BM = WR*32.
// Per K-chunk (BK=32): A f32 tile + B=W^T hi/lo bf16 staged via global_load_lds (16B),
// double-buffered, one barrier per chunk.
// Swizzles (rule #21): LDS dest linear; global source pre-permuted, ds_read un-permutes.
template <int K, int N, int WR, int WC>
__global__ void __launch_bounds__(WR * WC * 64, 4) gemm_mfma_kernel(
    const float* __restrict__ X, const unsigned short* __restrict__ Bth,
    const unsigned short* __restrict__ Btl, unsigned short* __restrict__ Y, int M) {
  constexpr int NW = WR * WC;
  constexpr int BM = WR * 32;
  constexpr int NI = K / 32;
  constexpr int ASLOTS = (BM / 8) / NW;   // 1KB A slots per wave
  constexpr int BSLOTS = (N / 8) / NW;    // 1KB B slots per wave (hi+lo combined)

  __shared__ float          As[2][BM * 32];
  __shared__ unsigned short Bs[2][2][N * 32];

  int tid = threadIdx.x;
  int lane = tid & 63, wid = tid >> 6;
  int wr = wid / WC, wc = wid % WC;
  int row0blk = blockIdx.x * BM;
  int row0 = row0blk + wr * 32;
  int rlo = lane & 15;
  int khi = lane >> 4;

  f32x4 acc[2][4] = {};

  auto stage = [&](int t, int buf) {
    int kb = t * 32;
#pragma unroll
    for (int i = 0; i < ASLOTS; ++i) {
      int slot = wid * ASLOTS + i;
      int rt = slot * 8 + (lane >> 3);
      int gr = row0blk + rt; gr = gr < M ? gr : M - 1;
      int gs = (lane & 7) ^ (lane >> 3);
      GLDS(X + (size_t)gr * K + kb + gs * 4, &As[buf][slot * 256]);
    }
#pragma unroll
    for (int i = 0; i < BSLOTS; ++i) {
      int slot = wid * BSLOTS + i;
      int half = slot / (N / 16);
      int idx = slot % (N / 16);
      const unsigned short* Wt = half ? Btl : Bth;
      int c = idx * 16 + (lane >> 2);
      int gs = (lane & 3) ^ (lane >> 4);
      GLDS(Wt + (size_t)c * K + kb + gs * 8, &Bs[buf][half][idx * 512]);
    }
  };

  stage(0, 0);
  __syncthreads();

#pragma unroll 1
  for (int t = 0; t < NI; ++t) {
    int buf = t & 1;
    if (t + 1 < NI) stage(t + 1, buf ^ 1);

    // A fragments (un-swizzle granule ^ (row&7)), f32 -> bf16 hi/lo
    bf16x8 ah[2], al[2];
#pragma unroll
    for (int m = 0; m < 2; ++m) {
      int rt = wr * 32 + m * 16 + rlo;
      int p0 = (khi * 2) ^ (rlo & 7), p1 = (khi * 2 + 1) ^ (rlo & 7);
      f32x4 v0 = *reinterpret_cast<const f32x4*>(&As[buf][rt * 32 + p0 * 4]);
      f32x4 v1 = *reinterpret_cast<const f32x4*>(&As[buf][rt * 32 + p1 * 4]);
      float f[8] = {v0.x, v0.y, v0.z, v0.w, v1.x, v1.y, v1.z, v1.w};
#pragma unroll
      for (int i = 0; i < 8; ++i) {
        __bf16 hv = (__bf16)f[i];
        ah[m][i] = hv;
        al[m][i] = (__bf16)(f[i] - (float)hv);
      }
    }
    // B fragments (un-swizzle granule ^ ((col>>2)&3))
    short8 bh[4], bl[4];
#pragma unroll
    for (int n = 0; n < 4; ++n) {
      int c = wc * 64 + n * 16 + rlo;
      int pos = khi ^ (rlo >> 2);
      bh[n] = *reinterpret_cast<const short8*>(&Bs[buf][0][c * 32 + pos * 8]);
      bl[n] = *reinterpret_cast<const short8*>(&Bs[buf][1][c * 32 + pos * 8]);
    }
#pragma unroll
    for (int m = 0; m < 2; ++m)
#pragma unroll
      for (int n = 0; n < 4; ++n)
        acc[m][n] = __builtin_amdgcn_mfma_f32_16x16x32_bf16(
            ah[m], __builtin_bit_cast(bf16x8, bh[n]), acc[m][n], 0, 0, 0);
#pragma unroll
    for (int m = 0; m < 2; ++m)
#pragma unroll
      for (int n = 0; n < 4; ++n)
        acc[m][n] = __builtin_amdgcn_mfma_f32_16x16x32_bf16(
            al[m], __builtin_bit_cast(bf16x8, bh[n]), acc[m][n], 0, 0, 0);
#pragma unroll
    for (int m = 0; m < 2; ++m)
#pragma unroll
      for (int n = 0; n < 4; ++n)
        acc[m][n] = __builtin_amdgcn_mfma_f32_16x16x32_bf16(
            ah[m], __builtin_bit_cast(bf16x8, bl[n]), acc[m][n], 0, 0, 0);
    __syncthreads();
  }

  // C/D layout: col = lane&15, row = (lane>>4)*4 + reg; store bf16 (RNE)
#pragma unroll
  for (int m = 0; m < 2; ++m)
#pragma unroll
    for (int j = 0; j < 4; ++j) {
      int row = row0 + m * 16 + khi * 4 + j;
      if (row < M) {
#pragma unroll
        for (int n = 0; n < 4; ++n) {
          __bf16 q = (__bf16)acc[m][n][j];
          Y[(size_t)row * N + wc * 64 + n * 16 + rlo] = __builtin_bit_cast(unsigned short, q);
        }
      }
    }
}

// ---------------- CSR aggregation over bf16 features ----------------
// out[n] (f32) = bias + sum_e w*feat_bf16[row];  F/8 lanes per node (short8 = 8 bf16/lane),
// 4-deep edge unroll; edge = u32 (row:16 | f16 norm:16)
template <int F, bool RELU>
__global__ void __launch_bounds__(256) agg_kernel(const unsigned short* __restrict__ feat,
                                                  const int* __restrict__ offs,
                                                  const unsigned int* __restrict__ edges,
                                                  const float* __restrict__ bias,
                                                  float* __restrict__ out, int n) {
  constexpr int LPN = F / 8;        // lanes per node (16 for F=128, 8 for F=64)
  constexpr int NPW = 64 / LPN;     // nodes per wave (4 / 8)
  constexpr int NPB = 4 * NPW;      // nodes per 256-thread block
  int wid = threadIdx.x >> 6;
  int lane = threadIdx.x & 63;
  int node = blockIdx.x * NPB + wid * NPW + lane / LPN;
  int lf = (lane % LPN) * 8;        // feature offset (8 bf16 per lane)
  if (node >= n) return;
  int e0 = offs[node], e1 = offs[node + 1];

  float acc[8];
#pragma unroll
  for (int j = 0; j < 8; ++j) acc[j] = bias[lf + j];

  auto fmaEdge = [&](unsigned int q) {
    float w = (float)__builtin_bit_cast(_Float16, (unsigned short)(q >> 16));
    int row = (int)(q & 0xFFFFu);
    short8 v = *reinterpret_cast<const short8*>(&feat[(size_t)row * F + lf]);
#pragma unroll
    for (int j = 0; j < 8; ++j)
      acc[j] = fmaf(w, bf2f((unsigned short)v[j]), acc[j]);
  };

  int e = e0;
  for (; e + 4 <= e1; e += 4) {
    unsigned int q0 = edges[e], q1 = edges[e + 1], q2 = edges[e + 2], q3 = edges[e + 3];
    fmaEdge(q0); fmaEdge(q1); fmaEdge(q2); fmaEdge(q3);
  }
  for (; e < e1; ++e) fmaEdge(edges[e]);

  if (RELU) {
#pragma unroll
    for (int j = 0; j < 8; ++j) acc[j] = fmaxf(acc[j], 0.f);
  }
  float4 o0 = make_float4(acc[0], acc[1], acc[2], acc[3]);
  float4 o1 = make_float4(acc[4], acc[5], acc[6], acc[7]);
  *reinterpret_cast<float4*>(&out[(size_t)node * F + lf]) = o0;
  *reinterpret_cast<float4*>(&out[(size_t)node * F + lf + 4]) = o1;
}

// ---------------- launch ----------------

extern "C" void kernel_launch(void* const* d_in, const int* in_sizes, int n_in,
                              void* d_out, int out_size, void* d_ws, size_t ws_size,
                              hipStream_t stream) {
  const float* x  = (const float*)d_in[0];
  const int*   ei = (const int*)d_in[1];     // [2, E] int
  const float* ew = (const float*)d_in[2];
  const float* W1 = (const float*)d_in[3];
  const float* b1 = (const float*)d_in[4];
  const float* W2 = (const float*)d_in[5];
  const float* b2 = (const float*)d_in[6];
  float* out = (float*)d_out;

  const int N = NNODES, E = NEDGES, EP = NNODES + NEDGES;
  const int NB = (N + 1023) / 1024;          // scan blocks (49)

  char* p = (char*)d_ws;
  auto alloc = [&](size_t bytes) { char* r = p; p += (bytes + 255) & ~(size_t)255; return r; };
  unsigned long long* packed = (unsigned long long*)alloc((size_t)N * 32); // 1/32B sector
  float* dinv   = (float*)alloc((size_t)N * 4);
  int*   counts = (int*)  alloc((size_t)N * 4);
  int*   offs   = (int*)  alloc((size_t)(N + 1) * 4);
  int*   bsum   = (int*)  alloc((size_t)64 * 4);
  unsigned short* rank = (unsigned short*)alloc((size_t)E * 2);
  unsigned int* edges  = (unsigned int*)alloc((size_t)EP * 4);  // (row:16|f16 norm:16)
  unsigned short* xw = (unsigned short*)alloc((size_t)N * HID_C * 2); // bf16 pre-agg (reused as h2)
  float* h      = (float*)alloc((size_t)N * HID_C * 4); // layer1 output (f32)
  unsigned short* W1th = (unsigned short*)alloc((size_t)IN_C * HID_C * 2);
  unsigned short* W1tl = (unsigned short*)alloc((size_t)IN_C * HID_C * 2);
  unsigned short* W2th = (unsigned short*)alloc((size_t)HID_C * OUT_C * 2);
  unsigned short* W2tl = (unsigned short*)alloc((size_t)HID_C * OUT_C * 2);

  clear_kernel<<<(N * 2 + 255) / 256, 256, 0, stream>>>((int4*)packed, N * 2);
  deg_count_kernel<<<(E + 255) / 256, 256, 0, stream>>>(ei, ew, packed, rank, E);
  decode_kernel<<<(N + 255) / 256, 256, 0, stream>>>(packed, dinv, counts, N);
  scan_partial_kernel<<<NB, 256, 0, stream>>>(counts, bsum, N);
  scan_bsum_kernel<<<1, 64, 0, stream>>>(bsum, NB);
  scan_final_kernel<<<NB, 256, 0, stream>>>(counts, bsum, offs, N);
  fill_kernel<<<(EP + 255) / 256, 256, 0, stream>>>(ei, ew, dinv, offs, rank, edges, E, N);
  wsplit_kernel<<<(IN_C * HID_C + 255) / 256, 256, 0, stream>>>(W1, W1th, W1tl, IN_C, HID_C);
  wsplit_kernel<<<(HID_C * OUT_C + 255) / 256, 256, 0, stream>>>(W2, W2th, W2tl, HID_C, OUT_C);

  // layer 1: xw = bf16(x @ W1) ; h = relu(agg(xw) + b1)   [BM=128, N=128, 8 waves]
  gemm_mfma_kernel<IN_C, HID_C, 4, 2><<<(N + 127) / 128, 512, 0, stream>>>(x, W1th, W1tl, xw, N);
  agg_kernel<HID_C, true><<<(N + 15) / 16, 256, 0, stream>>>(xw, offs, edges, b1, h, N);

  // layer 2: h2 = bf16(h @ W2) ; out = agg(h2) + b2       [BM=256, N=64, 8 waves]
  gemm_mfma_kernel<HID_C, OUT_C, 8, 1><<<(N + 255) / 256, 512, 0, stream>>>(h, W2th, W2tl, xw, N);
  agg_kernel<OUT_C, false><<<(N + 31) / 32, 256, 0, stream>>>(xw, offs, edges, b2, out, N);
}

// Round 12
// 147.159 us; speedup vs baseline: 3.0218x; 1.1047x over previous
//
#include <hip/hip_runtime.h>

#define NNODES 50000
#define NEDGES 800000
#define IN_C   512
#define HID_C  128
#define OUT_C  64

typedef float  f32x4  __attribute__((ext_vector_type(4)));
typedef __bf16 bf16x8 __attribute__((ext_vector_type(8)));
typedef short  short8 __attribute__((ext_vector_type(8)));

#define GLDS(src, dst) \
  __builtin_amdgcn_global_load_lds( \
      (const __attribute__((address_space(1))) unsigned int*)(src), \
      (__attribute__((address_space(3))) unsigned int*)(dst), 16, 0, 0)

__device__ __forceinline__ float bf2f(unsigned short u) {
  unsigned int x = (unsigned int)u << 16;
  return __builtin_bit_cast(float, x);
}

// ---------------- prep0: clear packed + split/transpose W1,W2 (fused) ----------------
// packed: deg+count in ONE u64/node (bits[0:20)=count, [20:64)=deg*2^24), 1 per 32B sector.

__device__ __forceinline__ void wsplit_one(const float* __restrict__ W,
                                           unsigned short* __restrict__ Th,
                                           unsigned short* __restrict__ Tl,
                                           int K, int N, int id) {
  int k = id % K, n = id / K;           // consecutive id -> consecutive k (coalesced writes)
  float f = W[(size_t)k * N + n];
  __bf16 hb = (__bf16)f;
  __bf16 lb = (__bf16)(f - (float)hb);
  Th[id] = __builtin_bit_cast(unsigned short, hb);
  Tl[id] = __builtin_bit_cast(unsigned short, lb);
}

__global__ void __launch_bounds__(256) prep0_kernel(
    int4* __restrict__ packed4, int nclear4,
    const float* __restrict__ W1, unsigned short* __restrict__ W1th,
    unsigned short* __restrict__ W1tl,
    const float* __restrict__ W2, unsigned short* __restrict__ W2th,
    unsigned short* __restrict__ W2tl) {
  int id = blockIdx.x * blockDim.x + threadIdx.x;
  if (id < nclear4) { packed4[id] = make_int4(0, 0, 0, 0); return; }
  int s = id - nclear4;
  if (s < IN_C * HID_C) wsplit_one(W1, W1th, W1tl, IN_C, HID_C, s);
  else if (s < IN_C * HID_C + HID_C * OUT_C)
    wsplit_one(W2, W2th, W2tl, HID_C, OUT_C, s - IN_C * HID_C);
}

// ---------------- split-bf16 MFMA GEMM body (shared by fused + standalone) ----------------
// Y[M,N] = X[M,K] @ W[K,N] -> bf16 (RNE);  Y ~= Xh@Wh + Xl@Wh + Xh@Wl  (Xl@Wl dropped)
// Per K-chunk (BK=32): A f32 tile + B=W^T hi/lo bf16 staged via global_load_lds (16B),
// double-buffered, one barrier per chunk. Source-swizzled/read-unswizzled (rule #21).
template <int K, int N, int WR, int WC>
__device__ __forceinline__ void gemm_body(const float* __restrict__ X,
                                          const unsigned short* __restrict__ Bth,
                                          const unsigned short* __restrict__ Btl,
                                          unsigned short* __restrict__ Y, int M, int bid) {
  constexpr int NW = WR * WC;
  constexpr int BM = WR * 32;
  constexpr int NI = K / 32;
  constexpr int ASLOTS = (BM / 8) / NW;
  constexpr int BSLOTS = (N / 8) / NW;

  __shared__ float          As[2][BM * 32];
  __shared__ unsigned short Bs[2][2][N * 32];

  int tid = threadIdx.x;
  int lane = tid & 63, wid = tid >> 6;
  int wr = wid / WC, wc = wid % WC;
  int row0blk = bid * BM;
  int row0 = row0blk + wr * 32;
  int rlo = lane & 15;
  int khi = lane >> 4;

  f32x4 acc[2][4] = {};

  auto stage = [&](int t, int buf) {
    int kb = t * 32;
#pragma unroll
    for (int i = 0; i < ASLOTS; ++i) {
      int slot = wid * ASLOTS + i;
      int rt = slot * 8 + (lane >> 3);
      int gr = row0blk + rt; gr = gr < M ? gr : M - 1;
      int gs = (lane & 7) ^ (lane >> 3);
      GLDS(X + (size_t)gr * K + kb + gs * 4, &As[buf][slot * 256]);
    }
#pragma unroll
    for (int i = 0; i < BSLOTS; ++i) {
      int slot = wid * BSLOTS + i;
      int half = slot / (N / 16);
      int idx = slot % (N / 16);
      const unsigned short* Wt = half ? Btl : Bth;
      int c = idx * 16 + (lane >> 2);
      int gs = (lane & 3) ^ (lane >> 4);
      GLDS(Wt + (size_t)c * K + kb + gs * 8, &Bs[buf][half][idx * 512]);
    }
  };

  stage(0, 0);
  __syncthreads();

#pragma unroll 1
  for (int t = 0; t < NI; ++t) {
    int buf = t & 1;
    if (t + 1 < NI) stage(t + 1, buf ^ 1);

    bf16x8 ah[2], al[2];
#pragma unroll
    for (int m = 0; m < 2; ++m) {
      int rt = wr * 32 + m * 16 + rlo;
      int p0 = (khi * 2) ^ (rlo & 7), p1 = (khi * 2 + 1) ^ (rlo & 7);
      f32x4 v0 = *reinterpret_cast<const f32x4*>(&As[buf][rt * 32 + p0 * 4]);
      f32x4 v1 = *reinterpret_cast<const f32x4*>(&As[buf][rt * 32 + p1 * 4]);
      float f[8] = {v0.x, v0.y, v0.z, v0.w, v1.x, v1.y, v1.z, v1.w};
#pragma unroll
      for (int i = 0; i < 8; ++i) {
        __bf16 hv = (__bf16)f[i];
        ah[m][i] = hv;
        al[m][i] = (__bf16)(f[i] - (float)hv);
      }
    }
    short8 bh[4], bl[4];
#pragma unroll
    for (int n = 0; n < 4; ++n) {
      int c = wc * 64 + n * 16 + rlo;
      int pos = khi ^ (rlo >> 2);
      bh[n] = *reinterpret_cast<const short8*>(&Bs[buf][0][c * 32 + pos * 8]);
      bl[n] = *reinterpret_cast<const short8*>(&Bs[buf][1][c * 32 + pos * 8]);
    }
#pragma unroll
    for (int m = 0; m < 2; ++m)
#pragma unroll
      for (int n = 0; n < 4; ++n)
        acc[m][n] = __builtin_amdgcn_mfma_f32_16x16x32_bf16(
            ah[m], __builtin_bit_cast(bf16x8, bh[n]), acc[m][n], 0, 0, 0);
#pragma unroll
    for (int m = 0; m < 2; ++m)
#pragma unroll
      for (int n = 0; n < 4; ++n)
        acc[m][n] = __builtin_amdgcn_mfma_f32_16x16x32_bf16(
            al[m], __builtin_bit_cast(bf16x8, bh[n]), acc[m][n], 0, 0, 0);
#pragma unroll
    for (int m = 0; m < 2; ++m)
#pragma unroll
      for (int n = 0; n < 4; ++n)
        acc[m][n] = __builtin_amdgcn_mfma_f32_16x16x32_bf16(
            ah[m], __builtin_bit_cast(bf16x8, bl[n]), acc[m][n], 0, 0, 0);
    __syncthreads();
  }

  // C/D layout: col = lane&15, row = (lane>>4)*4 + reg; store bf16 (RNE)
#pragma unroll
  for (int m = 0; m < 2; ++m)
#pragma unroll
    for (int j = 0; j < 4; ++j) {
      int row = row0 + m * 16 + khi * 4 + j;
      if (row < M) {
#pragma unroll
        for (int n = 0; n < 4; ++n) {
          __bf16 q = (__bf16)acc[m][n][j];
          Y[(size_t)row * N + wc * 64 + n * 16 + rlo] = __builtin_bit_cast(unsigned short, q);
        }
      }
    }
}

// ---------------- fused: gemm1 (blocks [0,ngemm)) ∥ deg_count (rest) ----------------
// Independent inputs/outputs; gemm is compute/LDS-bound, deg_count far-atomic-bound.
// gemm blocks first in grid -> dispatched first -> both proceed concurrently.
__global__ void __launch_bounds__(512, 4) fused_gemm1_deg_kernel(
    const float* __restrict__ X, const unsigned short* __restrict__ Bth,
    const unsigned short* __restrict__ Btl, unsigned short* __restrict__ Y, int M,
    int ngemm, const int* __restrict__ ei, const float* __restrict__ ew,
    unsigned long long* __restrict__ packed, unsigned short* __restrict__ rank, int nE) {
  if ((int)blockIdx.x < ngemm) {
    gemm_body<IN_C, HID_C, 4, 2>(X, Bth, Btl, Y, M, blockIdx.x);
  } else {
    int e = ((int)blockIdx.x - ngemm) * 512 + (int)threadIdx.x;
    if (e < nE) {
      int c = ei[nE + e];               // destination
      unsigned int fx = __float2uint_rn(ew[e] * 16777216.0f);   // ew in [0,1)
      unsigned long long old =
          atomicAdd(&packed[(size_t)c * 4], ((unsigned long long)fx << 20) | 1ULL);
      rank[e] = (unsigned short)(old & 0xFFFFFULL);   // edges-before-me at this dest
    }
  }
}

// standalone gemm (layer 2)
template <int K, int N, int WR, int WC>
__global__ void __launch_bounds__(WR * WC * 64, 4) gemm_mfma_kernel(
    const float* __restrict__ X, const unsigned short* __restrict__ Bth,
    const unsigned short* __restrict__ Btl, unsigned short* __restrict__ Y, int M) {
  gemm_body<K, N, WR, WC>(X, Bth, Btl, Y, M, blockIdx.x);
}

// ---------------- decode + scan_partial (fused): packed -> dinv,counts + block sums ----

__global__ void __launch_bounds__(256) decode_scan_kernel(
    const unsigned long long* __restrict__ packed, float* __restrict__ dinv,
    int* __restrict__ counts, int* __restrict__ bsum, int n) {
  int t = threadIdx.x;
  int i0 = blockIdx.x * 1024 + t * 4;
  int s = 0;
#pragma unroll
  for (int j = 0; j < 4; ++j) {
    int i = i0 + j;
    if (i < n) {
      unsigned long long p = packed[(size_t)i * 4];
      int cnt = (int)(p & 0xFFFFFULL) + 1;                     // + self-loop slot
      counts[i] = cnt;
      float deg = (float)((double)(p >> 20) * (1.0 / 16777216.0) + 1.0);
      dinv[i] = rsqrtf(deg);
      s += cnt;
    }
  }
#pragma unroll
  for (int off = 32; off; off >>= 1) s += __shfl_down(s, off);
  __shared__ int ws[4];
  if ((t & 63) == 0) ws[t >> 6] = s;
  __syncthreads();
  if (t == 0) bsum[blockIdx.x] = ws[0] + ws[1] + ws[2] + ws[3];
}

__global__ void scan_bsum_kernel(int* __restrict__ bsum, int nb) {  // 1 block, 64 thr; nb<=64
  int lane = threadIdx.x;
  int orig = lane < nb ? bsum[lane] : 0;
  int v = orig;
#pragma unroll
  for (int off = 1; off < 64; off <<= 1) {
    int u = __shfl_up(v, off);
    if (lane >= off) v += u;
  }
  if (lane < nb) bsum[lane] = v - orig;   // exclusive
}

__global__ void __launch_bounds__(256) scan_final_kernel(const int* __restrict__ counts,
                                                         const int* __restrict__ bscan,
                                                         int* __restrict__ offs, int n) {
  int t = threadIdx.x;
  int lane = t & 63, wid = t >> 6;
  int b = blockIdx.x;
  int i0 = b * 1024 + t * 4;
  int c[4];
#pragma unroll
  for (int j = 0; j < 4; ++j) c[j] = (i0 + j < n) ? counts[i0 + j] : 0;
  int s = c[0] + c[1] + c[2] + c[3];
  int v = s;
#pragma unroll
  for (int off = 1; off < 64; off <<= 1) {
    int u = __shfl_up(v, off);
    if (lane >= off) v += u;
  }
  __shared__ int wtot[4];
  if (lane == 63) wtot[wid] = v;
  __syncthreads();
  int wpre = 0;
#pragma unroll
  for (int w = 0; w < 4; ++w) if (w < wid) wpre += wtot[w];
  int p = bscan[b] + wpre + (v - s);
#pragma unroll
  for (int j = 0; j < 4; ++j) {
    if (i0 + j < n) offs[i0 + j] = p;
    p += c[j];
  }
  if (b == gridDim.x - 1 && t == 255)
    offs[n] = bscan[b] + wtot[0] + wtot[1] + wtot[2] + wtot[3];
}

// fill CSR, ATOMIC-FREE: pos = offs[c] + 1 + rank[e]; record u32 (row:16 | f16 norm:16).
// Non-temporal scattered stores (random 4B -> avoid write-allocate RMW where possible).
__global__ void fill_kernel(const int* __restrict__ ei, const float* __restrict__ ew,
                            const float* __restrict__ dinv, const int* __restrict__ offs,
                            const unsigned short* __restrict__ rank,
                            unsigned int* __restrict__ edges, int nE, int nN) {
  int i = blockIdx.x * blockDim.x + threadIdx.x;
  if (i < nN) {                       // self-loop of node i (offs monotone -> near-coalesced)
    float di = dinv[i];
    _Float16 hf = (_Float16)(di * di);
    unsigned int rec = (unsigned int)i |
                       ((unsigned int)__builtin_bit_cast(unsigned short, hf) << 16);
    __builtin_nontemporal_store(rec, &edges[offs[i]]);
  } else if (i < nN + nE) {
    int e = i - nN;
    int r = ei[e], c = ei[nE + e];
    float w = dinv[r] * ew[e] * dinv[c];
    _Float16 hf = (_Float16)w;
    int pos = offs[c] + 1 + (int)rank[e];
    unsigned int rec = (unsigned int)r |
                       ((unsigned int)__builtin_bit_cast(unsigned short, hf) << 16);
    __builtin_nontemporal_store(rec, &edges[pos]);
  }
}

// ---------------- CSR aggregation over bf16 features ----------------
// out[n] (f32) = bias + sum_e w*feat_bf16[row];  F/8 lanes/node (short8), 4-deep unroll
template <int F, bool RELU>
__global__ void __launch_bounds__(256) agg_kernel(const unsigned short* __restrict__ feat,
                                                  const int* __restrict__ offs,
                                                  const unsigned int* __restrict__ edges,
                                                  const float* __restrict__ bias,
                                                  float* __restrict__ out, int n) {
  constexpr int LPN = F / 8;
  constexpr int NPW = 64 / LPN;
  constexpr int NPB = 4 * NPW;
  int wid = threadIdx.x >> 6;
  int lane = threadIdx.x & 63;
  int node = blockIdx.x * NPB + wid * NPW + lane / LPN;
  int lf = (lane % LPN) * 8;
  if (node >= n) return;
  int e0 = offs[node], e1 = offs[node + 1];

  float acc[8];
#pragma unroll
  for (int j = 0; j < 8; ++j) acc[j] = bias[lf + j];

  auto fmaEdge = [&](unsigned int q) {
    float w = (float)__builtin_bit_cast(_Float16, (unsigned short)(q >> 16));
    int row = (int)(q & 0xFFFFu);
    short8 v = *reinterpret_cast<const short8*>(&feat[(size_t)row * F + lf]);
#pragma unroll
    for (int j = 0; j < 8; ++j)
      acc[j] = fmaf(w, bf2f((unsigned short)v[j]), acc[j]);
  };

  int e = e0;
  for (; e + 4 <= e1; e += 4) {
    unsigned int q0 = edges[e], q1 = edges[e + 1], q2 = edges[e + 2], q3 = edges[e + 3];
    fmaEdge(q0); fmaEdge(q1); fmaEdge(q2); fmaEdge(q3);
  }
  for (; e < e1; ++e) fmaEdge(edges[e]);

  if (RELU) {
#pragma unroll
    for (int j = 0; j < 8; ++j) acc[j] = fmaxf(acc[j], 0.f);
  }
  float4 o0 = make_float4(acc[0], acc[1], acc[2], acc[3]);
  float4 o1 = make_float4(acc[4], acc[5], acc[6], acc[7]);
  *reinterpret_cast<float4*>(&out[(size_t)node * F + lf]) = o0;
  *reinterpret_cast<float4*>(&out[(size_t)node * F + lf + 4]) = o1;
}

// ---------------- launch ----------------

extern "C" void kernel_launch(void* const* d_in, const int* in_sizes, int n_in,
                              void* d_out, int out_size, void* d_ws, size_t ws_size,
                              hipStream_t stream) {
  const float* x  = (const float*)d_in[0];
  const int*   ei = (const int*)d_in[1];     // [2, E] int
  const float* ew = (const float*)d_in[2];
  const float* W1 = (const float*)d_in[3];
  const float* b1 = (const float*)d_in[4];
  const float* W2 = (const float*)d_in[5];
  const float* b2 = (const float*)d_in[6];
  float* out = (float*)d_out;

  const int N = NNODES, E = NEDGES, EP = NNODES + NEDGES;
  const int NB = (N + 1023) / 1024;          // scan blocks (49)

  char* p = (char*)d_ws;
  auto alloc = [&](size_t bytes) { char* r = p; p += (bytes + 255) & ~(size_t)255; return r; };
  unsigned long long* packed = (unsigned long long*)alloc((size_t)N * 32); // 1/32B sector
  float* dinv   = (float*)alloc((size_t)N * 4);
  int*   counts = (int*)  alloc((size_t)N * 4);
  int*   offs   = (int*)  alloc((size_t)(N + 1) * 4);
  int*   bsum   = (int*)  alloc((size_t)64 * 4);
  unsigned short* rank = (unsigned short*)alloc((size_t)E * 2);
  unsigned int* edges  = (unsigned int*)alloc((size_t)EP * 4);  // (row:16|f16 norm:16)
  unsigned short* xw = (unsigned short*)alloc((size_t)N * HID_C * 2); // bf16 pre-agg / h2
  float* h      = (float*)alloc((size_t)N * HID_C * 4); // layer1 output (f32)
  unsigned short* W1th = (unsigned short*)alloc((size_t)IN_C * HID_C * 2);
  unsigned short* W1tl = (unsigned short*)alloc((size_t)IN_C * HID_C * 2);
  unsigned short* W2th = (unsigned short*)alloc((size_t)HID_C * OUT_C * 2);
  unsigned short* W2tl = (unsigned short*)alloc((size_t)HID_C * OUT_C * 2);

  // prep0: clear packed (100000 int4) + wsplit W1,W2 (73728 elems)
  const int NCLEAR4 = N * 32 / 16;
  const int PREP0 = NCLEAR4 + IN_C * HID_C + HID_C * OUT_C;
  prep0_kernel<<<(PREP0 + 255) / 256, 256, 0, stream>>>(
      (int4*)packed, NCLEAR4, W1, W1th, W1tl, W2, W2th, W2tl);

  // fused: gemm1 (391 blocks) ∥ deg_count (1563 blocks)
  const int NGEMM = (N + 127) / 128;
  const int NDEG = (E + 511) / 512;
  fused_gemm1_deg_kernel<<<NGEMM + NDEG, 512, 0, stream>>>(
      x, W1th, W1tl, xw, N, NGEMM, ei, ew, packed, rank, E);

  decode_scan_kernel<<<NB, 256, 0, stream>>>(packed, dinv, counts, bsum, N);
  scan_bsum_kernel<<<1, 64, 0, stream>>>(bsum, NB);
  scan_final_kernel<<<NB, 256, 0, stream>>>(counts, bsum, offs, N);
  fill_kernel<<<(EP + 255) / 256, 256, 0, stream>>>(ei, ew, dinv, offs, rank, edges, E, N);

  // layer 1 agg: h = relu(agg(xw) + b1)
  agg_kernel<HID_C, true><<<(N + 15) / 16, 256, 0, stream>>>(xw, offs, edges, b1, h, N);

  // layer 2: h2 = bf16(h @ W2) ; out = agg(h2) + b2   [BM=256, N=64, 8 waves]
  gemm_mfma_kernel<HID_C, OUT_C, 8, 1><<<(N + 255) / 256, 512, 0, stream>>>(h, W2th, W2tl, xw, N);
  agg_kernel<OUT_C, false><<<(N + 31) / 32, 256, 0, stream>>>(xw, offs, edges, b2, out, N);
}